// Round 1
// baseline (1417.886 us; speedup 1.0000x reference)
//
#include <hip/hip_runtime.h>

#define N_NODES 100000
#define N_EDGES 1600000
#define FDIM 64
#define GAUSS 5

// ---------------------------------------------------------------------------
// X0 = relu(h @ lin0_w + lin0_b)   [N,64]@[64,64]
// block 256 = 4 rows x 64 cols, weights in LDS
__global__ __launch_bounds__(256) void k_lin0(const float* __restrict__ h,
                                              const float* __restrict__ w,
                                              const float* __restrict__ b,
                                              float* __restrict__ x0) {
    __shared__ float wl[64 * 64];
    for (int i = threadIdx.x; i < 64 * 64; i += 256) wl[i] = w[i];
    __syncthreads();
    const int row = blockIdx.x * 4 + (threadIdx.x >> 6);
    const int col = threadIdx.x & 63;
    const float* hr = h + (size_t)row * 64;
    float acc = b[col];
#pragma unroll
    for (int k = 0; k < 64; k += 4) {
        const float4 hv = *(const float4*)(hr + k);  // same addr across wave -> broadcast
        acc += hv.x * wl[(k + 0) * 64 + col] + hv.y * wl[(k + 1) * 64 + col] +
               hv.z * wl[(k + 2) * 64 + col] + hv.w * wl[(k + 3) * 64 + col];
    }
    x0[(size_t)row * 64 + col] = fmaxf(acc, 0.f);
}

// ---------------------------------------------------------------------------
// Per-node projections for one conv layer:
//   Pd[n][0:64]   = x[n] @ wf[0:64]     (dst-side, filter)
//   Pd[n][64:128] = x[n] @ ws[0:64]     (dst-side, soft)
//   Ps[n][0:64]   = x[n] @ wf[64:128]   (src-side, filter)
//   Ps[n][64:128] = x[n] @ ws[64:128]   (src-side, soft)
// grid (3125, 4): 32 rows per block, blockIdx.y selects which 64x64 slice.
__global__ __launch_bounds__(256) void k_proj(const float* __restrict__ x,
                                              const float* __restrict__ wf,
                                              const float* __restrict__ ws,
                                              float* __restrict__ Pd,
                                              float* __restrict__ Ps) {
    __shared__ float wl[64 * 64];
    __shared__ float xl[32 * 64];
    const int g = blockIdx.y;  // 0:f/dst 1:s/dst 2:f/src 3:s/src
    const float* wsrc = (g & 1) ? ws : wf;
    const int rbase = (g & 2) ? 64 : 0;
    const int nbase = blockIdx.x * 32;
    for (int i = threadIdx.x; i < 4096; i += 256) wl[i] = wsrc[rbase * 64 + i];
    for (int i = threadIdx.x; i < 2048; i += 256) xl[i] = x[(size_t)nbase * 64 + i];
    __syncthreads();
    const int col = threadIdx.x & 63;
    const int rsub = threadIdx.x >> 6;
    float acc[8] = {0.f, 0.f, 0.f, 0.f, 0.f, 0.f, 0.f, 0.f};
#pragma unroll 4
    for (int k = 0; k < 64; k += 4) {
        const float w0 = wl[(k + 0) * 64 + col];
        const float w1 = wl[(k + 1) * 64 + col];
        const float w2 = wl[(k + 2) * 64 + col];
        const float w3 = wl[(k + 3) * 64 + col];
#pragma unroll
        for (int r = 0; r < 8; r++) {
            const float4 xv = *(const float4*)&xl[(rsub + r * 4) * 64 + k];  // broadcast
            acc[r] += xv.x * w0 + xv.y * w1 + xv.z * w2 + xv.w * w3;
        }
    }
    float* out = (g & 2) ? Ps : Pd;
    const int coff = (g & 1) ? 64 : 0;
#pragma unroll
    for (int r = 0; r < 8; r++) {
        out[(size_t)(nbase + rsub + r * 4) * 128 + coff + col] = acc[r];
    }
}

// ---------------------------------------------------------------------------
// Per-edge gated message + scatter-add.
//   e5 = relu(edge_attr @ short_w + short_b)                   (recomputed, 5x5)
//   zf = Pd[dst][0:64] + Ps[src][0:64]  + e5 @ wfE + bf
//   zs = Pd[dst][64:]  + Ps[src][64:]   + e5 @ wsE + bs
//   agg[dst] += sigmoid(zf) * softplus(zs)
// block 256 = 4 edges x 64 lanes (one wave per edge).
__global__ __launch_bounds__(256) void k_msg(const int* __restrict__ ei,
                                             const float* __restrict__ eattr,
                                             const float* __restrict__ sw,
                                             const float* __restrict__ sb,
                                             const float* __restrict__ wfE,
                                             const float* __restrict__ bf,
                                             const float* __restrict__ wsE,
                                             const float* __restrict__ bs,
                                             const float* __restrict__ Pd,
                                             const float* __restrict__ Ps,
                                             float* __restrict__ agg) {
    __shared__ float wfl[5 * 64], wsl[5 * 64], bfl[64], bsl[64], swl[25], sbl[5];
    const int t = threadIdx.x;
    for (int i = t; i < 320; i += 256) { wfl[i] = wfE[i]; wsl[i] = wsE[i]; }
    if (t < 64) { bfl[t] = bf[t]; bsl[t] = bs[t]; }
    if (t >= 64 && t < 89) swl[t - 64] = sw[t - 64];
    if (t >= 96 && t < 101) sbl[t - 96] = sb[t - 96];
    __syncthreads();

    const int e = blockIdx.x * 4 + (t >> 6);
    const int lane = t & 63;
    const int s = ei[e];
    const int d = ei[N_EDGES + e];

    float ea[GAUSS];
#pragma unroll
    for (int j = 0; j < GAUSS; j++) ea[j] = eattr[(size_t)e * GAUSS + j];
    float e5[GAUSS];
#pragma unroll
    for (int k = 0; k < GAUSS; k++) {
        float a = sbl[k];
#pragma unroll
        for (int j = 0; j < GAUSS; j++) a += ea[j] * swl[j * GAUSS + k];
        e5[k] = fmaxf(a, 0.f);
    }

    const float* pdr = Pd + (size_t)d * 128;
    const float* psr = Ps + (size_t)s * 128;
    float zf = pdr[lane] + psr[lane] + bfl[lane];
    float zs = pdr[64 + lane] + psr[64 + lane] + bsl[lane];
#pragma unroll
    for (int k = 0; k < GAUSS; k++) {
        zf += e5[k] * wfl[k * 64 + lane];
        zs += e5[k] * wsl[k * 64 + lane];
    }
    const float sig = 1.f / (1.f + __expf(-zf));
    const float sp = fmaxf(zs, 0.f) + log1pf(__expf(-fabsf(zs)));
    atomicAdd(&agg[(size_t)d * 64 + lane], sig * sp);
}

// ---------------------------------------------------------------------------
// In-place relu over n4 float4s.
__global__ __launch_bounds__(256) void k_relu(float4* __restrict__ x, int n4) {
    for (int i = blockIdx.x * 256 + threadIdx.x; i < n4; i += gridDim.x * 256) {
        float4 v = x[i];
        v.x = fmaxf(v.x, 0.f);
        v.y = fmaxf(v.y, 0.f);
        v.z = fmaxf(v.z, 0.f);
        v.w = fmaxf(v.w, 0.f);
        x[i] = v;
    }
}

// ---------------------------------------------------------------------------
extern "C" void kernel_launch(void* const* d_in, const int* in_sizes, int n_in,
                              void* d_out, int out_size, void* d_ws, size_t ws_size,
                              hipStream_t stream) {
    const float* h       = (const float*)d_in[0];
    const int*   ei      = (const int*)d_in[1];
    // d_in[2] edge_weight: unused by reference
    const float* eattr   = (const float*)d_in[3];
    // d_in[4] data: unused
    const float* lin0_w  = (const float*)d_in[5];
    const float* lin0_b  = (const float*)d_in[6];
    const float* short_w = (const float*)d_in[7];
    const float* short_b = (const float*)d_in[8];
    const float* conv_f_w = (const float*)d_in[9];
    const float* conv_f_b = (const float*)d_in[10];
    const float* conv_s_w = (const float*)d_in[11];
    const float* conv_s_b = (const float*)d_in[12];

    float* X0 = (float*)d_ws;                    // [N,64]
    float* X1 = X0 + (size_t)N_NODES * 64;       // [N,64]
    float* Pd = X1 + (size_t)N_NODES * 64;       // [N,128]
    float* Ps = Pd + (size_t)N_NODES * 128;      // [N,128]
    float* out = (float*)d_out;

    k_lin0<<<N_NODES / 4, 256, 0, stream>>>(h, lin0_w, lin0_b, X0);

    for (int i = 0; i < 2; i++) {
        const float* wf = conv_f_w + (size_t)i * 133 * 64;
        const float* ws = conv_s_w + (size_t)i * 133 * 64;
        const float* xin = i ? X1 : X0;
        float* agg = i ? out : X1;

        dim3 pg(N_NODES / 32, 4);
        k_proj<<<pg, 256, 0, stream>>>(xin, wf, ws, Pd, Ps);
        hipMemcpyAsync(agg, xin, (size_t)N_NODES * 64 * sizeof(float),
                       hipMemcpyDeviceToDevice, stream);
        k_msg<<<N_EDGES / 4, 256, 0, stream>>>(ei, eattr, short_w, short_b,
                                               wf + 128 * 64, conv_f_b + (size_t)i * 64,
                                               ws + 128 * 64, conv_s_b + (size_t)i * 64,
                                               Pd, Ps, agg);
        k_relu<<<2048, 256, 0, stream>>>((float4*)agg, N_NODES * 64 / 4);
    }
}

// Round 2
// 763.192 us; speedup vs baseline: 1.8578x; 1.8578x over previous
//
#include <hip/hip_runtime.h>

#define NN 100000
#define NE 1600000
#define NSB 391  // ceil(NN/256) scan blocks

static __device__ __forceinline__ unsigned f2bf(float x) {
    unsigned b = __float_as_uint(x);
    return (b + 0x7FFFu + ((b >> 16) & 1u)) >> 16;  // RNE bf16 bits
}
static __device__ __forceinline__ float bflo(unsigned u) { return __uint_as_float(u << 16); }
static __device__ __forceinline__ float bfhi(unsigned u) { return __uint_as_float(u & 0xFFFF0000u); }

// ---------------------------------------------------------------------------
// X0 = relu(h @ lin0_w + lin0_b)
__global__ __launch_bounds__(256) void k_lin0(const float* __restrict__ h,
                                              const float* __restrict__ w,
                                              const float* __restrict__ b,
                                              float* __restrict__ x0) {
    __shared__ float wl[64 * 64];
    for (int i = threadIdx.x; i < 64 * 64; i += 256) wl[i] = w[i];
    __syncthreads();
    const int row = blockIdx.x * 4 + (threadIdx.x >> 6);
    const int col = threadIdx.x & 63;
    const float* hr = h + (size_t)row * 64;
    float acc = b[col];
#pragma unroll
    for (int k = 0; k < 64; k += 4) {
        const float4 hv = *(const float4*)(hr + k);
        acc += hv.x * wl[(k + 0) * 64 + col] + hv.y * wl[(k + 1) * 64 + col] +
               hv.z * wl[(k + 2) * 64 + col] + hv.w * wl[(k + 3) * 64 + col];
    }
    x0[(size_t)row * 64 + col] = fmaxf(acc, 0.f);
}

// ---------------------------------------------------------------------------
// Counting sort of edges by dst: histogram -> scan -> scatter
__global__ __launch_bounds__(256) void k_hist(const int* __restrict__ ei, int* __restrict__ cnt) {
    const int e = blockIdx.x * 256 + threadIdx.x;
    atomicAdd(&cnt[ei[NE + e]], 1);
}

__global__ __launch_bounds__(256) void k_scan1(const int* __restrict__ cnt,
                                               int* __restrict__ offs, int* __restrict__ bsum) {
    __shared__ int sm[256];
    const int t = threadIdx.x;
    const int i = blockIdx.x * 256 + t;
    const int v = (i < NN) ? cnt[i] : 0;
    sm[t] = v;
    __syncthreads();
    for (int off = 1; off < 256; off <<= 1) {
        const int x = (t >= off) ? sm[t - off] : 0;
        __syncthreads();
        sm[t] += x;
        __syncthreads();
    }
    if (i < NN) offs[i] = sm[t] - v;  // exclusive within block
    if (t == 255) bsum[blockIdx.x] = sm[255];
}

__global__ __launch_bounds__(512) void k_scan2(int* __restrict__ bsum) {
    __shared__ int sm[512];
    const int t = threadIdx.x;
    const int v = (t < NSB) ? bsum[t] : 0;
    sm[t] = v;
    __syncthreads();
    for (int off = 1; off < 512; off <<= 1) {
        const int x = (t >= off) ? sm[t - off] : 0;
        __syncthreads();
        sm[t] += x;
        __syncthreads();
    }
    if (t < NSB) bsum[t] = sm[t] - v;  // exclusive block offsets
}

__global__ __launch_bounds__(256) void k_scan3(int* __restrict__ offs, const int* __restrict__ bsum) {
    const int i = blockIdx.x * 256 + threadIdx.x;
    if (i < NN) offs[i] += bsum[blockIdx.x];
    if (i == 0) offs[NN] = NE;
}

// scatter: meta[pos] = { src, e5 packed bf16 } grouped by dst
__global__ __launch_bounds__(256) void k_scatter(const int* __restrict__ ei,
                                                 const float* __restrict__ eattr,
                                                 const float* __restrict__ sw,
                                                 const float* __restrict__ sb,
                                                 int* __restrict__ head,
                                                 uint4* __restrict__ meta) {
    __shared__ float swl[25], sbl[5];
    if (threadIdx.x < 25) swl[threadIdx.x] = sw[threadIdx.x];
    if (threadIdx.x >= 32 && threadIdx.x < 37) sbl[threadIdx.x - 32] = sb[threadIdx.x - 32];
    __syncthreads();
    const int e = blockIdx.x * 256 + threadIdx.x;
    const int s = ei[e];
    const int d = ei[NE + e];
    float ea[5];
#pragma unroll
    for (int j = 0; j < 5; j++) ea[j] = eattr[(size_t)e * 5 + j];
    unsigned u5[5];
#pragma unroll
    for (int k = 0; k < 5; k++) {
        float a = sbl[k];
#pragma unroll
        for (int j = 0; j < 5; j++) a += ea[j] * swl[j * 5 + k];
        u5[k] = f2bf(fmaxf(a, 0.f));
    }
    uint4 m;
    m.x = (unsigned)s;
    m.y = u5[0] | (u5[1] << 16);
    m.z = u5[2] | (u5[3] << 16);
    m.w = u5[4];
    const int pos = atomicAdd(&head[d], 1);
    meta[pos] = m;
}

// ---------------------------------------------------------------------------
// Per-node projections, bf16-packed (f,s) pairs:
//   g==0: Pd[n][c] = pack(x[n]@wf[0:64]+bf, x[n]@ws[0:64]+bs)   (dst side, bias folded)
//   g==1: Ps[n][c] = pack(x[n]@wf[64:128],  x[n]@ws[64:128])    (src side)
__global__ __launch_bounds__(256) void k_proj(const float* __restrict__ x,
                                              const float* __restrict__ wf,
                                              const float* __restrict__ ws,
                                              const float* __restrict__ bfv,
                                              const float* __restrict__ bsv,
                                              unsigned* __restrict__ Pd,
                                              unsigned* __restrict__ Ps) {
    __shared__ float wfl[64 * 64];
    __shared__ float wsl[64 * 64];
    __shared__ float xl[32 * 64];
    const int g = blockIdx.y;
    const int rbase = g ? 64 : 0;
    const int nbase = blockIdx.x * 32;
    for (int i = threadIdx.x; i < 4096; i += 256) {
        wfl[i] = wf[rbase * 64 + i];
        wsl[i] = ws[rbase * 64 + i];
    }
    for (int i = threadIdx.x; i < 2048; i += 256) xl[i] = x[(size_t)nbase * 64 + i];
    __syncthreads();
    const int col = threadIdx.x & 63;
    const int rsub = threadIdx.x >> 6;
    float af[8] = {0, 0, 0, 0, 0, 0, 0, 0};
    float as[8] = {0, 0, 0, 0, 0, 0, 0, 0};
#pragma unroll 4
    for (int k = 0; k < 64; k += 4) {
        const float f0 = wfl[(k + 0) * 64 + col], f1 = wfl[(k + 1) * 64 + col];
        const float f2 = wfl[(k + 2) * 64 + col], f3 = wfl[(k + 3) * 64 + col];
        const float s0 = wsl[(k + 0) * 64 + col], s1 = wsl[(k + 1) * 64 + col];
        const float s2 = wsl[(k + 2) * 64 + col], s3 = wsl[(k + 3) * 64 + col];
#pragma unroll
        for (int r = 0; r < 8; r++) {
            const float4 xv = *(const float4*)&xl[(rsub + r * 4) * 64 + k];
            af[r] += xv.x * f0 + xv.y * f1 + xv.z * f2 + xv.w * f3;
            as[r] += xv.x * s0 + xv.y * s1 + xv.z * s2 + xv.w * s3;
        }
    }
    const float bfc = g ? 0.f : bfv[col];
    const float bsc = g ? 0.f : bsv[col];
    unsigned* out = g ? Ps : Pd;
#pragma unroll
    for (int r = 0; r < 8; r++) {
        out[(size_t)(nbase + rsub + r * 4) * 64 + col] =
            f2bf(af[r] + bfc) | (f2bf(as[r] + bsc) << 16);
    }
}

// ---------------------------------------------------------------------------
// Segment aggregation: one wave per dst node, edges pre-sorted by dst.
// out[n] = relu(x[n] + sum_edges sigmoid(zf)*softplus(zs)), no atomics.
__global__ __launch_bounds__(256) void k_seg(const int* __restrict__ offs,
                                             const uint4* __restrict__ meta,
                                             const unsigned* __restrict__ Pd,
                                             const unsigned* __restrict__ Ps,
                                             const float* __restrict__ wfE,
                                             const float* __restrict__ wsE,
                                             const float* __restrict__ xin,
                                             float* __restrict__ out) {
    __shared__ float wfl[320], wsl[320];
    for (int i = threadIdx.x; i < 320; i += 256) {
        wfl[i] = wfE[i];
        wsl[i] = wsE[i];
    }
    __syncthreads();
    const int n = blockIdx.x * 4 + (threadIdx.x >> 6);
    const int lane = threadIdx.x & 63;
    const int start = offs[n];
    const int end = offs[n + 1];
    const unsigned pd = Pd[(size_t)n * 64 + lane];
    const float pdf = bflo(pd);
    const float pds = bfhi(pd);
    const float wf0 = wfl[lane], wf1 = wfl[64 + lane], wf2 = wfl[128 + lane],
                wf3 = wfl[192 + lane], wf4 = wfl[256 + lane];
    const float ws0 = wsl[lane], ws1 = wsl[64 + lane], ws2 = wsl[128 + lane],
                ws3 = wsl[192 + lane], ws4 = wsl[256 + lane];
    float acc = 0.f;
    for (int i = start; i < end; i++) {
        const uint4 m = meta[i];                          // same addr across wave: broadcast
        const unsigned ps = Ps[(size_t)m.x * 64 + lane];  // the one random 256B gather
        const float e50 = bflo(m.y), e51 = bfhi(m.y);
        const float e52 = bflo(m.z), e53 = bfhi(m.z);
        const float e54 = bflo(m.w);
        float zf = pdf + bflo(ps);
        float zs = pds + bfhi(ps);
        zf += e50 * wf0 + e51 * wf1 + e52 * wf2 + e53 * wf3 + e54 * wf4;
        zs += e50 * ws0 + e51 * ws1 + e52 * ws2 + e53 * ws3 + e54 * ws4;
        const float sig = 1.f / (1.f + __expf(-zf));
        const float sp = fmaxf(zs, 0.f) + __logf(1.f + __expf(-fabsf(zs)));
        acc += sig * sp;
    }
    out[(size_t)n * 64 + lane] = fmaxf(xin[(size_t)n * 64 + lane] + acc, 0.f);
}

// ---------------------------------------------------------------------------
extern "C" void kernel_launch(void* const* d_in, const int* in_sizes, int n_in,
                              void* d_out, int out_size, void* d_ws, size_t ws_size,
                              hipStream_t stream) {
    const float* h = (const float*)d_in[0];
    const int* ei = (const int*)d_in[1];
    const float* eattr = (const float*)d_in[3];
    const float* lin0_w = (const float*)d_in[5];
    const float* lin0_b = (const float*)d_in[6];
    const float* short_w = (const float*)d_in[7];
    const float* short_b = (const float*)d_in[8];
    const float* conv_f_w = (const float*)d_in[9];
    const float* conv_f_b = (const float*)d_in[10];
    const float* conv_s_w = (const float*)d_in[11];
    const float* conv_s_b = (const float*)d_in[12];

    char* ws = (char*)d_ws;
    uint4* meta = (uint4*)ws;                          // [NE] 16B, 25.6 MB (aligned at base)
    float* X0 = (float*)(ws + (size_t)NE * 16);        // [NN*64] f32
    float* X1 = X0 + (size_t)NN * 64;                  // [NN*64] f32
    unsigned* Pd = (unsigned*)(X1 + (size_t)NN * 64);  // [NN*64] u32
    unsigned* Ps = Pd + (size_t)NN * 64;               // [NN*64] u32
    int* cnt = (int*)(Ps + (size_t)NN * 64);           // [NN]
    int* offs = cnt + NN;                              // [NN+1]
    int* head = offs + NN + 1;                         // [NN]
    int* bsum = head + NN;                             // [NSB]

    k_lin0<<<NN / 4, 256, 0, stream>>>(h, lin0_w, lin0_b, X0);

    hipMemsetAsync(cnt, 0, (size_t)NN * 4, stream);
    k_hist<<<NE / 256, 256, 0, stream>>>(ei, cnt);
    k_scan1<<<NSB, 256, 0, stream>>>(cnt, offs, bsum);
    k_scan2<<<1, 512, 0, stream>>>(bsum);
    k_scan3<<<NSB, 256, 0, stream>>>(offs, bsum);
    hipMemcpyAsync(head, offs, (size_t)NN * 4, hipMemcpyDeviceToDevice, stream);
    k_scatter<<<NE / 256, 256, 0, stream>>>(ei, eattr, short_w, short_b, head, meta);

    for (int i = 0; i < 2; i++) {
        const float* wf = conv_f_w + (size_t)i * 133 * 64;
        const float* wsv = conv_s_w + (size_t)i * 133 * 64;
        const float* bf = conv_f_b + (size_t)i * 64;
        const float* bs = conv_s_b + (size_t)i * 64;
        const float* xin = i ? X1 : X0;
        float* out = i ? (float*)d_out : X1;

        dim3 pg(NN / 32, 2);
        k_proj<<<pg, 256, 0, stream>>>(xin, wf, wsv, bf, bs, Pd, Ps);
        k_seg<<<NN / 4, 256, 0, stream>>>(offs, meta, Pd, Ps,
                                          wf + 128 * 64, wsv + 128 * 64, xin, out);
    }
}

// Round 3
// 636.525 us; speedup vs baseline: 2.2275x; 1.1990x over previous
//
#include <hip/hip_runtime.h>

#define NN 100000
#define NE 1600000
#define NSB 391  // ceil(NN/256) scan blocks

#define LOG2E 1.4426950408889634f
#define LN2 0.6931471805599453f

static __device__ __forceinline__ unsigned f2bf(float x) {
    unsigned b = __float_as_uint(x);
    return (b + 0x7FFFu + ((b >> 16) & 1u)) >> 16;  // RNE bf16 bits
}
static __device__ __forceinline__ float bflo(unsigned u) { return __uint_as_float(u << 16); }
static __device__ __forceinline__ float bfhi(unsigned u) { return __uint_as_float(u & 0xFFFF0000u); }

// ---------------------------------------------------------------------------
// X0 = relu(h @ lin0_w + lin0_b)
__global__ __launch_bounds__(256) void k_lin0(const float* __restrict__ h,
                                              const float* __restrict__ w,
                                              const float* __restrict__ b,
                                              float* __restrict__ x0) {
    __shared__ float wl[64 * 64];
    for (int i = threadIdx.x; i < 64 * 64; i += 256) wl[i] = w[i];
    __syncthreads();
    const int row = blockIdx.x * 4 + (threadIdx.x >> 6);
    const int col = threadIdx.x & 63;
    const float* hr = h + (size_t)row * 64;
    float acc = b[col];
#pragma unroll
    for (int k = 0; k < 64; k += 4) {
        const float4 hv = *(const float4*)(hr + k);
        acc += hv.x * wl[(k + 0) * 64 + col] + hv.y * wl[(k + 1) * 64 + col] +
               hv.z * wl[(k + 2) * 64 + col] + hv.w * wl[(k + 3) * 64 + col];
    }
    x0[(size_t)row * 64 + col] = fmaxf(acc, 0.f);
}

// ---------------------------------------------------------------------------
// Counting sort of edges by dst: histogram -> scan -> scatter
__global__ __launch_bounds__(256) void k_hist(const int* __restrict__ ei, int* __restrict__ cnt) {
    const int e = blockIdx.x * 256 + threadIdx.x;
    atomicAdd(&cnt[ei[NE + e]], 1);
}

__global__ __launch_bounds__(256) void k_scan1(const int* __restrict__ cnt,
                                               int* __restrict__ offs, int* __restrict__ bsum) {
    __shared__ int sm[256];
    const int t = threadIdx.x;
    const int i = blockIdx.x * 256 + t;
    const int v = (i < NN) ? cnt[i] : 0;
    sm[t] = v;
    __syncthreads();
    for (int off = 1; off < 256; off <<= 1) {
        const int x = (t >= off) ? sm[t - off] : 0;
        __syncthreads();
        sm[t] += x;
        __syncthreads();
    }
    if (i < NN) offs[i] = sm[t] - v;  // exclusive within block
    if (t == 255) bsum[blockIdx.x] = sm[255];
}

__global__ __launch_bounds__(512) void k_scan2(int* __restrict__ bsum) {
    __shared__ int sm[512];
    const int t = threadIdx.x;
    const int v = (t < NSB) ? bsum[t] : 0;
    sm[t] = v;
    __syncthreads();
    for (int off = 1; off < 512; off <<= 1) {
        const int x = (t >= off) ? sm[t - off] : 0;
        __syncthreads();
        sm[t] += x;
        __syncthreads();
    }
    if (t < NSB) bsum[t] = sm[t] - v;  // exclusive block offsets
}

__global__ __launch_bounds__(256) void k_scan3(int* __restrict__ offs, const int* __restrict__ bsum,
                                               int* __restrict__ head) {
    const int i = blockIdx.x * 256 + threadIdx.x;
    if (i < NN) {
        const int v = offs[i] + bsum[blockIdx.x];
        offs[i] = v;
        head[i] = v;
    }
    if (i == 0) offs[NN] = NE;
}

// scatter: meta[pos] = { src, e5 packed bf16 } grouped by dst
__global__ __launch_bounds__(256) void k_scatter(const int* __restrict__ ei,
                                                 const float* __restrict__ eattr,
                                                 const float* __restrict__ sw,
                                                 const float* __restrict__ sb,
                                                 int* __restrict__ head,
                                                 uint4* __restrict__ meta) {
    __shared__ float swl[25], sbl[5];
    if (threadIdx.x < 25) swl[threadIdx.x] = sw[threadIdx.x];
    if (threadIdx.x >= 32 && threadIdx.x < 37) sbl[threadIdx.x - 32] = sb[threadIdx.x - 32];
    __syncthreads();
    const int e = blockIdx.x * 256 + threadIdx.x;
    const int s = ei[e];
    const int d = ei[NE + e];
    float ea[5];
#pragma unroll
    for (int j = 0; j < 5; j++) ea[j] = eattr[(size_t)e * 5 + j];
    unsigned u5[5];
#pragma unroll
    for (int k = 0; k < 5; k++) {
        float a = sbl[k];
#pragma unroll
        for (int j = 0; j < 5; j++) a += ea[j] * swl[j * 5 + k];
        u5[k] = f2bf(fmaxf(a, 0.f));
    }
    uint4 m;
    m.x = (unsigned)s;
    m.y = u5[0] | (u5[1] << 16);
    m.z = u5[2] | (u5[3] << 16);
    m.w = u5[4];
    const int pos = atomicAdd(&head[d], 1);
    meta[pos] = m;
}

// ---------------------------------------------------------------------------
// Per-node projections, bf16-packed, LOG2E-scaled and sign-folded:
//   g==0: Pd[n][c] = pack(-log2e*(x@wf[0:64]+bf), log2e*(x@ws[0:64]+bs))
//   g==1: Ps[n][c] = pack(-log2e*(x@wf[64:128]), log2e*(x@ws[64:128]))
__global__ __launch_bounds__(256) void k_proj(const float* __restrict__ x,
                                              const float* __restrict__ wf,
                                              const float* __restrict__ ws,
                                              const float* __restrict__ bfv,
                                              const float* __restrict__ bsv,
                                              unsigned* __restrict__ Pd,
                                              unsigned* __restrict__ Ps) {
    __shared__ float wfl[64 * 64];
    __shared__ float wsl[64 * 64];
    __shared__ float xl[32 * 64];
    const int g = blockIdx.y;
    const int rbase = g ? 64 : 0;
    const int nbase = blockIdx.x * 32;
    for (int i = threadIdx.x; i < 4096; i += 256) {
        wfl[i] = wf[rbase * 64 + i];
        wsl[i] = ws[rbase * 64 + i];
    }
    for (int i = threadIdx.x; i < 2048; i += 256) xl[i] = x[(size_t)nbase * 64 + i];
    __syncthreads();
    const int col = threadIdx.x & 63;
    const int rsub = threadIdx.x >> 6;
    float af[8] = {0, 0, 0, 0, 0, 0, 0, 0};
    float as[8] = {0, 0, 0, 0, 0, 0, 0, 0};
#pragma unroll 4
    for (int k = 0; k < 64; k += 4) {
        const float f0 = wfl[(k + 0) * 64 + col], f1 = wfl[(k + 1) * 64 + col];
        const float f2 = wfl[(k + 2) * 64 + col], f3 = wfl[(k + 3) * 64 + col];
        const float s0 = wsl[(k + 0) * 64 + col], s1 = wsl[(k + 1) * 64 + col];
        const float s2 = wsl[(k + 2) * 64 + col], s3 = wsl[(k + 3) * 64 + col];
#pragma unroll
        for (int r = 0; r < 8; r++) {
            const float4 xv = *(const float4*)&xl[(rsub + r * 4) * 64 + k];
            af[r] += xv.x * f0 + xv.y * f1 + xv.z * f2 + xv.w * f3;
            as[r] += xv.x * s0 + xv.y * s1 + xv.z * s2 + xv.w * s3;
        }
    }
    const float bfc = g ? 0.f : bfv[col];
    const float bsc = g ? 0.f : bsv[col];
    unsigned* out = g ? Ps : Pd;
#pragma unroll
    for (int r = 0; r < 8; r++) {
        out[(size_t)(nbase + rsub + r * 4) * 64 + col] =
            f2bf(-LOG2E * (af[r] + bfc)) | (f2bf(LOG2E * (as[r] + bsc)) << 16);
    }
}

// ---------------------------------------------------------------------------
// Segment aggregation: one wave per dst node, edges pre-sorted by dst.
// Scalarized meta path (readfirstlane -> s_load + SALU unpack), log2-domain
// gate math, 2-deep meta / 1-deep Ps software pipeline. No atomics.
__global__ __launch_bounds__(256) void k_seg(const int* __restrict__ offs,
                                             const uint4* __restrict__ meta,
                                             const unsigned* __restrict__ Pd,
                                             const unsigned* __restrict__ Ps,
                                             const float* __restrict__ wfE,
                                             const float* __restrict__ wsE,
                                             const float* __restrict__ xin,
                                             float* __restrict__ out) {
    __shared__ float wfl[320], wsl[320];
    for (int i = threadIdx.x; i < 320; i += 256) {
        wfl[i] = -LOG2E * wfE[i];  // f-side: negated log2e
        wsl[i] = LOG2E * wsE[i];   // s-side: log2e
    }
    __syncthreads();
    const int n = blockIdx.x * 4 + (threadIdx.x >> 6);
    const int lane = threadIdx.x & 63;
    const int start = __builtin_amdgcn_readfirstlane(offs[n]);
    const int end = __builtin_amdgcn_readfirstlane(offs[n + 1]);
    const unsigned pd = Pd[(size_t)n * 64 + lane];
    const float npdf = bflo(pd);
    const float pds = bfhi(pd);
    const float wf0 = wfl[lane], wf1 = wfl[64 + lane], wf2 = wfl[128 + lane],
                wf3 = wfl[192 + lane], wf4 = wfl[256 + lane];
    const float ws0 = wsl[lane], ws1 = wsl[64 + lane], ws2 = wsl[128 + lane],
                ws3 = wsl[192 + lane], ws4 = wsl[256 + lane];
    const float xv = xin[(size_t)n * 64 + lane];
    float acc = 0.f;
    if (start < end) {
        const int last = end - 1;
        uint4 m0 = meta[start];
        const int i1 = min(start + 1, last);
        uint4 m1 = meta[__builtin_amdgcn_readfirstlane(i1)];
        unsigned ps0 = Ps[(size_t)m0.x * 64 + lane];
        for (int i = start; i < end; i++) {
            // prefetch: meta 2 ahead, Ps 1 ahead
            const int i2 = min(i + 2, last);
            const uint4 m2 = meta[__builtin_amdgcn_readfirstlane(i2)];
            const unsigned ps1 = Ps[(size_t)m1.x * 64 + lane];
            // gate math in log2 domain
            float nzf = npdf + bflo(ps0);
            float zsp = pds + bfhi(ps0);
            const float e50 = bflo(m0.y), e51 = bfhi(m0.y);
            const float e52 = bflo(m0.z), e53 = bfhi(m0.z);
            const float e54 = bflo(m0.w);
            nzf = fmaf(e50, wf0, nzf);
            nzf = fmaf(e51, wf1, nzf);
            nzf = fmaf(e52, wf2, nzf);
            nzf = fmaf(e53, wf3, nzf);
            nzf = fmaf(e54, wf4, nzf);
            zsp = fmaf(e50, ws0, zsp);
            zsp = fmaf(e51, ws1, zsp);
            zsp = fmaf(e52, ws2, zsp);
            zsp = fmaf(e53, ws3, zsp);
            zsp = fmaf(e54, ws4, zsp);
            const float sig = __builtin_amdgcn_rcpf(1.f + exp2f(nzf));   // sigmoid(zf)
            const float g = fmaxf(zsp, 0.f) + log2f(1.f + exp2f(-fabsf(zsp)));
            acc = fmaf(sig, g, acc);  // true msg sum = LN2 * acc
            m0 = m1;
            m1 = m2;
            ps0 = ps1;
        }
    }
    out[(size_t)n * 64 + lane] = fmaxf(fmaf(acc, LN2, xv), 0.f);
}

// ---------------------------------------------------------------------------
extern "C" void kernel_launch(void* const* d_in, const int* in_sizes, int n_in,
                              void* d_out, int out_size, void* d_ws, size_t ws_size,
                              hipStream_t stream) {
    const float* h = (const float*)d_in[0];
    const int* ei = (const int*)d_in[1];
    const float* eattr = (const float*)d_in[3];
    const float* lin0_w = (const float*)d_in[5];
    const float* lin0_b = (const float*)d_in[6];
    const float* short_w = (const float*)d_in[7];
    const float* short_b = (const float*)d_in[8];
    const float* conv_f_w = (const float*)d_in[9];
    const float* conv_f_b = (const float*)d_in[10];
    const float* conv_s_w = (const float*)d_in[11];
    const float* conv_s_b = (const float*)d_in[12];

    char* ws = (char*)d_ws;
    uint4* meta = (uint4*)ws;                          // [NE] 16B, 25.6 MB
    float* X0 = (float*)(ws + (size_t)NE * 16);        // [NN*64] f32
    float* X1 = X0 + (size_t)NN * 64;                  // [NN*64] f32
    unsigned* Pd = (unsigned*)(X1 + (size_t)NN * 64);  // [NN*64] u32
    unsigned* Ps = Pd + (size_t)NN * 64;               // [NN*64] u32
    int* cnt = (int*)(Ps + (size_t)NN * 64);           // [NN]
    int* offs = cnt + NN;                              // [NN+1]
    int* head = offs + NN + 1;                         // [NN]
    int* bsum = head + NN;                             // [NSB]

    k_lin0<<<NN / 4, 256, 0, stream>>>(h, lin0_w, lin0_b, X0);

    hipMemsetAsync(cnt, 0, (size_t)NN * 4, stream);
    k_hist<<<NE / 256, 256, 0, stream>>>(ei, cnt);
    k_scan1<<<NSB, 256, 0, stream>>>(cnt, offs, bsum);
    k_scan2<<<1, 512, 0, stream>>>(bsum);
    k_scan3<<<NSB, 256, 0, stream>>>(offs, bsum, head);
    k_scatter<<<NE / 256, 256, 0, stream>>>(ei, eattr, short_w, short_b, head, meta);

    for (int i = 0; i < 2; i++) {
        const float* wf = conv_f_w + (size_t)i * 133 * 64;
        const float* wsv = conv_s_w + (size_t)i * 133 * 64;
        const float* bf = conv_f_b + (size_t)i * 64;
        const float* bs = conv_s_b + (size_t)i * 64;
        const float* xin = i ? X1 : X0;
        float* out = i ? (float*)d_out : X1;

        dim3 pg(NN / 32, 2);
        k_proj<<<pg, 256, 0, stream>>>(xin, wf, wsv, bf, bs, Pd, Ps);
        k_seg<<<NN / 4, 256, 0, stream>>>(offs, meta, Pd, Ps,
                                          wf + 128 * 64, wsv + 128 * 64, xin, out);
    }
}

// Round 4
// 516.607 us; speedup vs baseline: 2.7446x; 1.2321x over previous
//
#include <hip/hip_runtime.h>

#define NN 100000
#define NE 1600000
#define NSB 391  // ceil(NN/256) scan blocks

#define LOG2E 1.4426950408889634f
#define LN2 0.6931471805599453f

typedef short short4v __attribute__((ext_vector_type(4)));
typedef short short8v __attribute__((ext_vector_type(8)));
typedef float f32x4 __attribute__((ext_vector_type(4)));

static __device__ __forceinline__ unsigned f2bf(float x) {
    unsigned b = __float_as_uint(x);
    return (b + 0x7FFFu + ((b >> 16) & 1u)) >> 16;  // RNE bf16 bits
}
static __device__ __forceinline__ float bflo(unsigned u) { return __uint_as_float(u << 16); }
static __device__ __forceinline__ float bfhi(unsigned u) { return __uint_as_float(u & 0xFFFF0000u); }
static __device__ __forceinline__ short8v mk8(short4v a, short4v b) {
    short8v r;
    r[0] = a[0]; r[1] = a[1]; r[2] = a[2]; r[3] = a[3];
    r[4] = b[0]; r[5] = b[1]; r[6] = b[2]; r[7] = b[3];
    return r;
}

// ---------------------------------------------------------------------------
// X0 = relu(h @ lin0_w + lin0_b); also writes bf16 copy for the MFMA proj.
__global__ __launch_bounds__(256) void k_lin0(const float* __restrict__ h,
                                              const float* __restrict__ w,
                                              const float* __restrict__ b,
                                              float* __restrict__ x0,
                                              unsigned short* __restrict__ xb) {
    __shared__ float wl[64 * 64];
    for (int i = threadIdx.x; i < 64 * 64; i += 256) wl[i] = w[i];
    __syncthreads();
    const int row = blockIdx.x * 4 + (threadIdx.x >> 6);
    const int col = threadIdx.x & 63;
    const float* hr = h + (size_t)row * 64;
    float acc = b[col];
#pragma unroll
    for (int k = 0; k < 64; k += 4) {
        const float4 hv = *(const float4*)(hr + k);
        acc += hv.x * wl[(k + 0) * 64 + col] + hv.y * wl[(k + 1) * 64 + col] +
               hv.z * wl[(k + 2) * 64 + col] + hv.w * wl[(k + 3) * 64 + col];
    }
    const float r = fmaxf(acc, 0.f);
    x0[(size_t)row * 64 + col] = r;
    xb[(size_t)row * 64 + col] = (unsigned short)f2bf(r);
}

// ---------------------------------------------------------------------------
// Counting sort of edges by dst: histogram -> scan -> scatter
__global__ __launch_bounds__(256) void k_hist(const int* __restrict__ ei, int* __restrict__ cnt) {
    const int e = blockIdx.x * 256 + threadIdx.x;
    atomicAdd(&cnt[ei[NE + e]], 1);
}

__global__ __launch_bounds__(256) void k_scan1(const int* __restrict__ cnt,
                                               int* __restrict__ offs, int* __restrict__ bsum) {
    __shared__ int sm[256];
    const int t = threadIdx.x;
    const int i = blockIdx.x * 256 + t;
    const int v = (i < NN) ? cnt[i] : 0;
    sm[t] = v;
    __syncthreads();
    for (int off = 1; off < 256; off <<= 1) {
        const int x = (t >= off) ? sm[t - off] : 0;
        __syncthreads();
        sm[t] += x;
        __syncthreads();
    }
    if (i < NN) offs[i] = sm[t] - v;
    if (t == 255) bsum[blockIdx.x] = sm[255];
}

__global__ __launch_bounds__(512) void k_scan2(int* __restrict__ bsum) {
    __shared__ int sm[512];
    const int t = threadIdx.x;
    const int v = (t < NSB) ? bsum[t] : 0;
    sm[t] = v;
    __syncthreads();
    for (int off = 1; off < 512; off <<= 1) {
        const int x = (t >= off) ? sm[t - off] : 0;
        __syncthreads();
        sm[t] += x;
        __syncthreads();
    }
    if (t < NSB) bsum[t] = sm[t] - v;
}

__global__ __launch_bounds__(256) void k_scan3(int* __restrict__ offs, const int* __restrict__ bsum,
                                               int* __restrict__ head) {
    const int i = blockIdx.x * 256 + threadIdx.x;
    if (i < NN) {
        const int v = offs[i] + bsum[blockIdx.x];
        offs[i] = v;
        head[i] = v;
    }
    if (i == 0) offs[NN] = NE;
}

// scatter: meta[pos] = { src, e5 packed bf16 } grouped by dst
__global__ __launch_bounds__(256) void k_scatter(const int* __restrict__ ei,
                                                 const float* __restrict__ eattr,
                                                 const float* __restrict__ sw,
                                                 const float* __restrict__ sb,
                                                 int* __restrict__ head,
                                                 uint4* __restrict__ meta) {
    __shared__ float swl[25], sbl[5];
    if (threadIdx.x < 25) swl[threadIdx.x] = sw[threadIdx.x];
    if (threadIdx.x >= 32 && threadIdx.x < 37) sbl[threadIdx.x - 32] = sb[threadIdx.x - 32];
    __syncthreads();
    const int e = blockIdx.x * 256 + threadIdx.x;
    const int s = ei[e];
    const int d = ei[NE + e];
    float ea[5];
#pragma unroll
    for (int j = 0; j < 5; j++) ea[j] = eattr[(size_t)e * 5 + j];
    unsigned u5[5];
#pragma unroll
    for (int k = 0; k < 5; k++) {
        float a = sbl[k];
#pragma unroll
        for (int j = 0; j < 5; j++) a += ea[j] * swl[j * 5 + k];
        u5[k] = f2bf(fmaxf(a, 0.f));
    }
    uint4 m;
    m.x = (unsigned)s;
    m.y = u5[0] | (u5[1] << 16);
    m.z = u5[2] | (u5[3] << 16);
    m.w = u5[4];
    const int pos = atomicAdd(&head[d], 1);
    meta[pos] = m;
}

// ---------------------------------------------------------------------------
// Pack the 4 64x64 weight mats of one layer into MFMA B-fragment layout, bf16,
// LOG2E-scaled/sign-folded. mat: 0=dstF 1=dstS 2=srcF 3=srcS.
// Bp[(((mat*4+ct)*2+kh)*64 + lane)*8 + j] = bf16(scale * W[roff + k][ct*16 + (lane&15)])
//   k = kh*32 + (j<4 ? 4*(lane>>4)+j : 16 + 4*(lane>>4) + j-4)
__global__ __launch_bounds__(256) void k_wpack(const float* __restrict__ wf,
                                               const float* __restrict__ ws,
                                               unsigned short* __restrict__ Bp) {
    const int q = blockIdx.x * 256 + threadIdx.x;  // 2048 total
    const int m = q >> 9;
    const int rem = q & 511;
    const int ct = rem >> 7;
    const int kh = (rem >> 6) & 1;
    const int l = rem & 63;
    const float scale = (m & 1) ? LOG2E : -LOG2E;
    const float* src = (m & 1) ? ws : wf;
    const int roff = (m >> 1) ? 64 : 0;
    const int n = ct * 16 + (l & 15);
#pragma unroll
    for (int j = 0; j < 8; j++) {
        const int k = kh * 32 + ((j < 4) ? (4 * (l >> 4) + j) : (16 + 4 * (l >> 4) + j - 4));
        Bp[(size_t)q * 8 + j] = (unsigned short)f2bf(scale * src[(size_t)(roff + k) * 64 + n]);
    }
}

// ---------------------------------------------------------------------------
// MFMA projections: Pd[n][c] = pack(-log2e*(x@Wf_d+bf), log2e*(x@Ws_d+bs)),
//                   Ps[n][c] = pack(-log2e*(x@Wf_s),    log2e*(x@Ws_s))
// block = 4 waves; wave w handles col-tile w (16 cols); block handles 16 rows.
__global__ __launch_bounds__(256) void k_projm(const unsigned short* __restrict__ xb,
                                               const unsigned short* __restrict__ Bp,
                                               const float* __restrict__ bfv,
                                               const float* __restrict__ bsv,
                                               unsigned* __restrict__ Pd,
                                               unsigned* __restrict__ Ps) {
    __shared__ __align__(16) short xl[16 * 64];
    const int rowbase = blockIdx.x * 16;
    // stage 16x64 bf16 x-tile (512 uints, linear)
    {
        const unsigned* xsrc = (const unsigned*)(xb + (size_t)rowbase * 64);
        unsigned* xdst = (unsigned*)xl;
        xdst[threadIdx.x] = xsrc[threadIdx.x];
        xdst[threadIdx.x + 256] = xsrc[threadIdx.x + 256];
    }
    __syncthreads();
    const int ct = threadIdx.x >> 6;
    const int l = threadIdx.x & 63;
    const int lm = l & 15;
    const int g = l >> 4;
    // A fragments (shared across the 4 col-tiles' waves, each builds its own)
    const short* xrow = &xl[lm * 64];
    const short8v A0 = mk8(*(const short4v*)&xrow[g * 4], *(const short4v*)&xrow[16 + g * 4]);
    const short8v A1 = mk8(*(const short4v*)&xrow[32 + g * 4], *(const short4v*)&xrow[48 + g * 4]);
    // B fragments: 4 mats x 2 k-halves, 16B per lane
    const short* bp = (const short*)Bp;
    f32x4 acc[4];
#pragma unroll
    for (int m = 0; m < 4; m++) {
        const short8v B0 = *(const short8v*)&bp[((((m * 4 + ct) * 2 + 0) * 64 + l) * 8)];
        const short8v B1 = *(const short8v*)&bp[((((m * 4 + ct) * 2 + 1) * 64 + l) * 8)];
        f32x4 a = {0.f, 0.f, 0.f, 0.f};
        a = __builtin_amdgcn_mfma_f32_16x16x32_bf16(A0, B0, a, 0, 0, 0);
        a = __builtin_amdgcn_mfma_f32_16x16x32_bf16(A1, B1, a, 0, 0, 0);
        acc[m] = a;
    }
    const int col = ct * 16 + lm;
    const float bfb = -LOG2E * bfv[col];
    const float bsb = LOG2E * bsv[col];
#pragma unroll
    for (int reg = 0; reg < 4; reg++) {
        const int rowg = rowbase + g * 4 + reg;
        Pd[(size_t)rowg * 64 + col] = f2bf(acc[0][reg] + bfb) | (f2bf(acc[1][reg] + bsb) << 16);
        Ps[(size_t)rowg * 64 + col] = f2bf(acc[2][reg]) | (f2bf(acc[3][reg]) << 16);
    }
}

// ---------------------------------------------------------------------------
// Segment aggregation: one wave per dst node, edges pre-sorted by dst.
// Scalar meta path, raw v_exp/v_log/v_rcp transcendentals, log2-domain gates.
__global__ __launch_bounds__(256) void k_seg(const int* __restrict__ offs,
                                             const uint4* __restrict__ meta,
                                             const unsigned* __restrict__ Pd,
                                             const unsigned* __restrict__ Ps,
                                             const float* __restrict__ wfE,
                                             const float* __restrict__ wsE,
                                             const float* __restrict__ xin,
                                             float* __restrict__ out,
                                             unsigned short* __restrict__ xbout) {
    __shared__ float wfl[320], wsl[320];
    for (int i = threadIdx.x; i < 320; i += 256) {
        wfl[i] = -LOG2E * wfE[i];
        wsl[i] = LOG2E * wsE[i];
    }
    __syncthreads();
    const int n = blockIdx.x * 4 + (threadIdx.x >> 6);
    const int lane = threadIdx.x & 63;
    const int start = __builtin_amdgcn_readfirstlane(offs[n]);
    const int end = __builtin_amdgcn_readfirstlane(offs[n + 1]);
    const unsigned pd = Pd[(size_t)n * 64 + lane];
    const float npdf = bflo(pd);
    const float pds = bfhi(pd);
    const float wf0 = wfl[lane], wf1 = wfl[64 + lane], wf2 = wfl[128 + lane],
                wf3 = wfl[192 + lane], wf4 = wfl[256 + lane];
    const float ws0 = wsl[lane], ws1 = wsl[64 + lane], ws2 = wsl[128 + lane],
                ws3 = wsl[192 + lane], ws4 = wsl[256 + lane];
    const float xv = xin[(size_t)n * 64 + lane];
    float acc = 0.f;
    if (start < end) {
        const int last = end - 1;
        uint4 m0 = meta[start];
        const int i1 = min(start + 1, last);
        uint4 m1 = meta[__builtin_amdgcn_readfirstlane(i1)];
        unsigned ps0 = Ps[(size_t)m0.x * 64 + lane];
        for (int i = start; i < end; i++) {
            const int i2 = min(i + 2, last);
            const uint4 m2 = meta[__builtin_amdgcn_readfirstlane(i2)];
            const unsigned ps1 = Ps[(size_t)m1.x * 64 + lane];
            float nzf = npdf + bflo(ps0);
            float zsp = pds + bfhi(ps0);
            const float e50 = bflo(m0.y), e51 = bfhi(m0.y);
            const float e52 = bflo(m0.z), e53 = bfhi(m0.z);
            const float e54 = bflo(m0.w);
            nzf = fmaf(e50, wf0, nzf);
            nzf = fmaf(e51, wf1, nzf);
            nzf = fmaf(e52, wf2, nzf);
            nzf = fmaf(e53, wf3, nzf);
            nzf = fmaf(e54, wf4, nzf);
            zsp = fmaf(e50, ws0, zsp);
            zsp = fmaf(e51, ws1, zsp);
            zsp = fmaf(e52, ws2, zsp);
            zsp = fmaf(e53, ws3, zsp);
            zsp = fmaf(e54, ws4, zsp);
            const float sig = __builtin_amdgcn_rcpf(1.f + __builtin_amdgcn_exp2f(nzf));
            const float gg = fmaxf(zsp, 0.f) +
                             __builtin_amdgcn_logf(1.f + __builtin_amdgcn_exp2f(-fabsf(zsp)));
            acc = fmaf(sig, gg, acc);
            m0 = m1;
            m1 = m2;
            ps0 = ps1;
        }
    }
    const float res = fmaxf(fmaf(acc, LN2, xv), 0.f);
    out[(size_t)n * 64 + lane] = res;
    if (xbout) xbout[(size_t)n * 64 + lane] = (unsigned short)f2bf(res);
}

// ---------------------------------------------------------------------------
extern "C" void kernel_launch(void* const* d_in, const int* in_sizes, int n_in,
                              void* d_out, int out_size, void* d_ws, size_t ws_size,
                              hipStream_t stream) {
    const float* h = (const float*)d_in[0];
    const int* ei = (const int*)d_in[1];
    const float* eattr = (const float*)d_in[3];
    const float* lin0_w = (const float*)d_in[5];
    const float* lin0_b = (const float*)d_in[6];
    const float* short_w = (const float*)d_in[7];
    const float* short_b = (const float*)d_in[8];
    const float* conv_f_w = (const float*)d_in[9];
    const float* conv_f_b = (const float*)d_in[10];
    const float* conv_s_w = (const float*)d_in[11];
    const float* conv_s_b = (const float*)d_in[12];

    char* ws = (char*)d_ws;
    uint4* meta = (uint4*)ws;                             // [NE] 16B, 25.6 MB
    float* X0 = (float*)(ws + (size_t)NE * 16);           // [NN*64] f32
    float* X1 = X0 + (size_t)NN * 64;                     // [NN*64] f32
    unsigned* Pd = (unsigned*)(X1 + (size_t)NN * 64);     // [NN*64] u32
    unsigned* Ps = Pd + (size_t)NN * 64;                  // [NN*64] u32
    unsigned short* XB = (unsigned short*)(Ps + (size_t)NN * 64);  // [NN*64] bf16
    unsigned short* Bp = XB + (size_t)NN * 64;            // [16384] packed weights
    int* cnt = (int*)(Bp + 16384);                        // [NN]
    int* offs = cnt + NN;                                 // [NN+1]
    int* head = offs + NN + 1;                            // [NN]
    int* bsum = head + NN;                                // [NSB]

    k_lin0<<<NN / 4, 256, 0, stream>>>(h, lin0_w, lin0_b, X0, XB);

    hipMemsetAsync(cnt, 0, (size_t)NN * 4, stream);
    k_hist<<<NE / 256, 256, 0, stream>>>(ei, cnt);
    k_scan1<<<NSB, 256, 0, stream>>>(cnt, offs, bsum);
    k_scan2<<<1, 512, 0, stream>>>(bsum);
    k_scan3<<<NSB, 256, 0, stream>>>(offs, bsum, head);
    k_scatter<<<NE / 256, 256, 0, stream>>>(ei, eattr, short_w, short_b, head, meta);

    for (int i = 0; i < 2; i++) {
        const float* wf = conv_f_w + (size_t)i * 133 * 64;
        const float* wsv = conv_s_w + (size_t)i * 133 * 64;
        const float* bf = conv_f_b + (size_t)i * 64;
        const float* bs = conv_s_b + (size_t)i * 64;
        const float* xin = i ? X1 : X0;
        float* out = i ? (float*)d_out : X1;

        k_wpack<<<8, 256, 0, stream>>>(wf, wsv, Bp);
        k_projm<<<NN / 16, 256, 0, stream>>>(XB, Bp, bf, bs, Pd, Ps);
        k_seg<<<NN / 4, 256, 0, stream>>>(offs, meta, Pd, Ps,
                                          wf + 128 * 64, wsv + 128 * 64, xin, out,
                                          i ? (unsigned short*)nullptr : XB);
    }
}

// Round 6
// 450.657 us; speedup vs baseline: 3.1463x; 1.1463x over previous
//
#include <hip/hip_runtime.h>

#define NN 100000
#define NE 1600000
#define NSB 391  // ceil(NN/256) scan blocks

#define LOG2E 1.4426950408889634f
#define LN2 0.6931471805599453f

typedef short short4v __attribute__((ext_vector_type(4)));
typedef short short8v __attribute__((ext_vector_type(8)));
typedef float f32x4 __attribute__((ext_vector_type(4)));
typedef unsigned u32x4 __attribute__((ext_vector_type(4)));

static __device__ __forceinline__ unsigned f2bf(float x) {
    unsigned b = __float_as_uint(x);
    return (b + 0x7FFFu + ((b >> 16) & 1u)) >> 16;  // RNE bf16 bits
}
static __device__ __forceinline__ float bflo(unsigned u) { return __uint_as_float(u << 16); }
static __device__ __forceinline__ float bfhi(unsigned u) { return __uint_as_float(u & 0xFFFF0000u); }
static __device__ __forceinline__ int imin(int a, int b) { return a < b ? a : b; }
static __device__ __forceinline__ short8v mk8(short4v a, short4v b) {
    short8v r;
    r[0] = a[0]; r[1] = a[1]; r[2] = a[2]; r[3] = a[3];
    r[4] = b[0]; r[5] = b[1]; r[6] = b[2]; r[7] = b[3];
    return r;
}

// One edge's gated-message contribution (log2-domain).
static __device__ __forceinline__ float edge_acc(uint4 m, unsigned ps, float npdf, float pds,
                                                 const float* __restrict__ wfv,
                                                 const float* __restrict__ wsv, float acc) {
    float nzf = npdf + bflo(ps);
    float zsp = pds + bfhi(ps);
    const float e50 = bflo(m.y), e51 = bfhi(m.y);
    const float e52 = bflo(m.z), e53 = bfhi(m.z);
    const float e54 = bflo(m.w);
    nzf = fmaf(e50, wfv[0], nzf);
    nzf = fmaf(e51, wfv[1], nzf);
    nzf = fmaf(e52, wfv[2], nzf);
    nzf = fmaf(e53, wfv[3], nzf);
    nzf = fmaf(e54, wfv[4], nzf);
    zsp = fmaf(e50, wsv[0], zsp);
    zsp = fmaf(e51, wsv[1], zsp);
    zsp = fmaf(e52, wsv[2], zsp);
    zsp = fmaf(e53, wsv[3], zsp);
    zsp = fmaf(e54, wsv[4], zsp);
    const float sig = __builtin_amdgcn_rcpf(1.f + __builtin_amdgcn_exp2f(nzf));
    const float gg = fmaxf(zsp, 0.f) +
                     __builtin_amdgcn_logf(1.f + __builtin_amdgcn_exp2f(-fabsf(zsp)));
    return fmaf(sig, gg, acc);
}

// ---------------------------------------------------------------------------
// X0 = relu(h @ lin0_w + lin0_b); also writes bf16 copy for the MFMA proj.
__global__ __launch_bounds__(256) void k_lin0(const float* __restrict__ h,
                                              const float* __restrict__ w,
                                              const float* __restrict__ b,
                                              float* __restrict__ x0,
                                              unsigned short* __restrict__ xb) {
    __shared__ float wl[64 * 64];
    for (int i = threadIdx.x; i < 64 * 64; i += 256) wl[i] = w[i];
    __syncthreads();
    const int row = blockIdx.x * 4 + (threadIdx.x >> 6);
    const int col = threadIdx.x & 63;
    const float* hr = h + (size_t)row * 64;
    float acc = b[col];
#pragma unroll
    for (int k = 0; k < 64; k += 4) {
        const float4 hv = *(const float4*)(hr + k);
        acc += hv.x * wl[(k + 0) * 64 + col] + hv.y * wl[(k + 1) * 64 + col] +
               hv.z * wl[(k + 2) * 64 + col] + hv.w * wl[(k + 3) * 64 + col];
    }
    const float r = fmaxf(acc, 0.f);
    x0[(size_t)row * 64 + col] = r;
    xb[(size_t)row * 64 + col] = (unsigned short)f2bf(r);
}

// ---------------------------------------------------------------------------
// Counting sort of edges by dst: histogram -> scan -> scatter
__global__ __launch_bounds__(256) void k_hist(const int* __restrict__ ei, int* __restrict__ cnt) {
    const int e = blockIdx.x * 256 + threadIdx.x;
    atomicAdd(&cnt[ei[NE + e]], 1);
}

__global__ __launch_bounds__(256) void k_scan1(const int* __restrict__ cnt,
                                               int* __restrict__ offs, int* __restrict__ bsum) {
    __shared__ int sm[256];
    const int t = threadIdx.x;
    const int i = blockIdx.x * 256 + t;
    const int v = (i < NN) ? cnt[i] : 0;
    sm[t] = v;
    __syncthreads();
    for (int off = 1; off < 256; off <<= 1) {
        const int x = (t >= off) ? sm[t - off] : 0;
        __syncthreads();
        sm[t] += x;
        __syncthreads();
    }
    if (i < NN) offs[i] = sm[t] - v;
    if (t == 255) bsum[blockIdx.x] = sm[255];
}

__global__ __launch_bounds__(512) void k_scan2(int* __restrict__ bsum) {
    __shared__ int sm[512];
    const int t = threadIdx.x;
    const int v = (t < NSB) ? bsum[t] : 0;
    sm[t] = v;
    __syncthreads();
    for (int off = 1; off < 512; off <<= 1) {
        const int x = (t >= off) ? sm[t - off] : 0;
        __syncthreads();
        sm[t] += x;
        __syncthreads();
    }
    if (t < NSB) bsum[t] = sm[t] - v;
}

__global__ __launch_bounds__(256) void k_scan3(int* __restrict__ offs, const int* __restrict__ bsum,
                                               int* __restrict__ head) {
    const int i = blockIdx.x * 256 + threadIdx.x;
    if (i < NN) {
        const int v = offs[i] + bsum[blockIdx.x];
        offs[i] = v;
        head[i] = v;
    }
    if (i == 0) offs[NN] = NE;
}

// scatter: meta[pos] = { src, e5 packed bf16 } grouped by dst
__global__ __launch_bounds__(256) void k_scatter(const int* __restrict__ ei,
                                                 const float* __restrict__ eattr,
                                                 const float* __restrict__ sw,
                                                 const float* __restrict__ sb,
                                                 int* __restrict__ head,
                                                 uint4* __restrict__ meta) {
    __shared__ float swl[25], sbl[5];
    if (threadIdx.x < 25) swl[threadIdx.x] = sw[threadIdx.x];
    if (threadIdx.x >= 32 && threadIdx.x < 37) sbl[threadIdx.x - 32] = sb[threadIdx.x - 32];
    __syncthreads();
    const int e = blockIdx.x * 256 + threadIdx.x;
    const int s = ei[e];
    const int d = ei[NE + e];
    float ea[5];
#pragma unroll
    for (int j = 0; j < 5; j++) ea[j] = eattr[(size_t)e * 5 + j];
    unsigned u5[5];
#pragma unroll
    for (int k = 0; k < 5; k++) {
        float a = sbl[k];
#pragma unroll
        for (int j = 0; j < 5; j++) a += ea[j] * swl[j * 5 + k];
        u5[k] = f2bf(fmaxf(a, 0.f));
    }
    uint4 m;
    m.x = (unsigned)s;
    m.y = u5[0] | (u5[1] << 16);
    m.z = u5[2] | (u5[3] << 16);
    m.w = u5[4];
    const int pos = atomicAdd(&head[d], 1);
    meta[pos] = m;
}

// ---------------------------------------------------------------------------
// Pack the 4 64x64 weight mats of one layer into MFMA B-fragment layout, bf16,
// LOG2E-scaled/sign-folded. mat: 0=dstF 1=dstS 2=srcF 3=srcS.
__global__ __launch_bounds__(256) void k_wpack(const float* __restrict__ wf,
                                               const float* __restrict__ ws,
                                               unsigned short* __restrict__ Bp) {
    const int q = blockIdx.x * 256 + threadIdx.x;  // 2048 total
    const int m = q >> 9;
    const int rem = q & 511;
    const int ct = rem >> 7;
    const int kh = (rem >> 6) & 1;
    const int l = rem & 63;
    const float scale = (m & 1) ? LOG2E : -LOG2E;
    const float* src = (m & 1) ? ws : wf;
    const int roff = (m >> 1) ? 64 : 0;
    const int n = ct * 16 + (l & 15);
#pragma unroll
    for (int j = 0; j < 8; j++) {
        const int k = kh * 32 + ((j < 4) ? (4 * (l >> 4) + j) : (16 + 4 * (l >> 4) + j - 4));
        Bp[(size_t)q * 8 + j] = (unsigned short)f2bf(scale * src[(size_t)(roff + k) * 64 + n]);
    }
}

// ---------------------------------------------------------------------------
// MFMA projections, 32 rows per block (each wave: 1 col-tile x 2 row-tiles,
// B-fragments reused across row-tiles).
__global__ __launch_bounds__(256) void k_projm(const unsigned short* __restrict__ xb,
                                               const unsigned short* __restrict__ Bp,
                                               const float* __restrict__ bfv,
                                               const float* __restrict__ bsv,
                                               unsigned* __restrict__ Pd,
                                               unsigned* __restrict__ Ps) {
    __shared__ __align__(16) short xl[32 * 64];
    const int rowbase = blockIdx.x * 32;
    {
        const u32x4* xsrc = (const u32x4*)(xb + (size_t)rowbase * 64);  // 4096 B
        u32x4* xdst = (u32x4*)xl;
        xdst[threadIdx.x] = __builtin_nontemporal_load(&xsrc[threadIdx.x]);
    }
    __syncthreads();
    const int ct = threadIdx.x >> 6;
    const int l = threadIdx.x & 63;
    const int lm = l & 15;
    const int g = l >> 4;
    short8v A[2][2];
#pragma unroll
    for (int rt = 0; rt < 2; rt++) {
        const short* xrow = &xl[(rt * 16 + lm) * 64];
        A[rt][0] = mk8(*(const short4v*)&xrow[g * 4], *(const short4v*)&xrow[16 + g * 4]);
        A[rt][1] = mk8(*(const short4v*)&xrow[32 + g * 4], *(const short4v*)&xrow[48 + g * 4]);
    }
    const short* bp = (const short*)Bp;
    f32x4 acc[4][2];
#pragma unroll
    for (int m = 0; m < 4; m++) {
        const short8v B0 = *(const short8v*)&bp[(((m * 4 + ct) * 2 + 0) * 64 + l) * 8];
        const short8v B1 = *(const short8v*)&bp[(((m * 4 + ct) * 2 + 1) * 64 + l) * 8];
#pragma unroll
        for (int rt = 0; rt < 2; rt++) {
            f32x4 a = {0.f, 0.f, 0.f, 0.f};
            a = __builtin_amdgcn_mfma_f32_16x16x32_bf16(A[rt][0], B0, a, 0, 0, 0);
            a = __builtin_amdgcn_mfma_f32_16x16x32_bf16(A[rt][1], B1, a, 0, 0, 0);
            acc[m][rt] = a;
        }
    }
    const int col = ct * 16 + lm;
    const float bfb = -LOG2E * bfv[col];
    const float bsb = LOG2E * bsv[col];
#pragma unroll
    for (int rt = 0; rt < 2; rt++) {
#pragma unroll
        for (int reg = 0; reg < 4; reg++) {
            const int rowg = rowbase + rt * 16 + g * 4 + reg;
            Pd[(size_t)rowg * 64 + col] =
                f2bf(acc[0][rt][reg] + bfb) | (f2bf(acc[1][rt][reg] + bsb) << 16);
            Ps[(size_t)rowg * 64 + col] =
                f2bf(acc[2][rt][reg]) | (f2bf(acc[3][rt][reg]) << 16);
        }
    }
}

// ---------------------------------------------------------------------------
// Segment aggregation: one wave per dst node, edges pre-sorted by dst.
// 4-wide batched pipeline: meta prefetched 2 batches ahead (scalar loads),
// 4 independent Ps gathers in flight; peeled predicated last batch.
__global__ __launch_bounds__(256) void k_seg(const int* __restrict__ offs,
                                             const uint4* __restrict__ meta,
                                             const unsigned* __restrict__ Pd,
                                             const unsigned* __restrict__ Ps,
                                             const float* __restrict__ wfE,
                                             const float* __restrict__ wsE,
                                             const float* __restrict__ xin,
                                             float* __restrict__ out,
                                             unsigned short* __restrict__ xbout) {
    __shared__ float wfl[320], wsl[320];
    for (int i = threadIdx.x; i < 320; i += 256) {
        wfl[i] = -LOG2E * wfE[i];
        wsl[i] = LOG2E * wsE[i];
    }
    __syncthreads();
    const int n = blockIdx.x * 4 + (threadIdx.x >> 6);
    const int lane = threadIdx.x & 63;
    const int start = __builtin_amdgcn_readfirstlane(offs[n]);
    const int end = __builtin_amdgcn_readfirstlane(offs[n + 1]);
    const unsigned pd = __builtin_nontemporal_load(&Pd[(size_t)n * 64 + lane]);
    const float npdf = bflo(pd);
    const float pds = bfhi(pd);
    float wfv[5], wsv[5];
#pragma unroll
    for (int k = 0; k < 5; k++) {
        wfv[k] = wfl[k * 64 + lane];
        wsv[k] = wsl[k * 64 + lane];
    }
    const float xv = __builtin_nontemporal_load(&xin[(size_t)n * 64 + lane]);
    float acc = 0.f;
    const int cnt = end - start;
    if (cnt > 0) {
        const int last = end - 1;
        const int nbF = (cnt + 3) >> 2;
        uint4 M0[4], M1[4];
        unsigned PS0[4];
#pragma unroll
        for (int j = 0; j < 4; j++) M0[j] = meta[imin(start + j, last)];
#pragma unroll
        for (int j = 0; j < 4; j++) M1[j] = meta[imin(start + 4 + j, last)];
#pragma unroll
        for (int j = 0; j < 4; j++) PS0[j] = Ps[(size_t)M0[j].x * 64 + lane];
        for (int b = 0; b < nbF - 1; b++) {
            const int base2 = start + (b + 2) * 4;
            uint4 M2[4];
            unsigned PS1[4];
#pragma unroll
            for (int j = 0; j < 4; j++) M2[j] = meta[imin(base2 + j, last)];
#pragma unroll
            for (int j = 0; j < 4; j++) PS1[j] = Ps[(size_t)M1[j].x * 64 + lane];
#pragma unroll
            for (int j = 0; j < 4; j++) acc = edge_acc(M0[j], PS0[j], npdf, pds, wfv, wsv, acc);
#pragma unroll
            for (int j = 0; j < 4; j++) {
                M0[j] = M1[j];
                M1[j] = M2[j];
                PS0[j] = PS1[j];
            }
        }
        const int lb = start + (nbF - 1) * 4;
#pragma unroll
        for (int j = 0; j < 4; j++)
            if (lb + j < end) acc = edge_acc(M0[j], PS0[j], npdf, pds, wfv, wsv, acc);
    }
    const float res = fmaxf(fmaf(acc, LN2, xv), 0.f);
    if (xbout) {
        out[(size_t)n * 64 + lane] = res;  // X1: re-read next layer, keep cached
        xbout[(size_t)n * 64 + lane] = (unsigned short)f2bf(res);
    } else {
        __builtin_nontemporal_store(res, &out[(size_t)n * 64 + lane]);  // final output
    }
}

// ---------------------------------------------------------------------------
extern "C" void kernel_launch(void* const* d_in, const int* in_sizes, int n_in,
                              void* d_out, int out_size, void* d_ws, size_t ws_size,
                              hipStream_t stream) {
    const float* h = (const float*)d_in[0];
    const int* ei = (const int*)d_in[1];
    const float* eattr = (const float*)d_in[3];
    const float* lin0_w = (const float*)d_in[5];
    const float* lin0_b = (const float*)d_in[6];
    const float* short_w = (const float*)d_in[7];
    const float* short_b = (const float*)d_in[8];
    const float* conv_f_w = (const float*)d_in[9];
    const float* conv_f_b = (const float*)d_in[10];
    const float* conv_s_w = (const float*)d_in[11];
    const float* conv_s_b = (const float*)d_in[12];

    char* ws = (char*)d_ws;
    uint4* meta = (uint4*)ws;                             // [NE] 16B, 25.6 MB
    float* X0 = (float*)(ws + (size_t)NE * 16);           // [NN*64] f32
    float* X1 = X0 + (size_t)NN * 64;                     // [NN*64] f32
    unsigned* Pd = (unsigned*)(X1 + (size_t)NN * 64);     // [NN*64] u32
    unsigned* Ps = Pd + (size_t)NN * 64;                  // [NN*64] u32
    unsigned short* XB = (unsigned short*)(Ps + (size_t)NN * 64);  // [NN*64] bf16
    unsigned short* Bp = XB + (size_t)NN * 64;            // [16384] packed weights
    int* cnt = (int*)(Bp + 16384);                        // [NN]
    int* offs = cnt + NN;                                 // [NN+1]
    int* head = offs + NN + 1;                            // [NN]
    int* bsum = head + NN;                                // [NSB]

    k_lin0<<<NN / 4, 256, 0, stream>>>(h, lin0_w, lin0_b, X0, XB);

    hipMemsetAsync(cnt, 0, (size_t)NN * 4, stream);
    k_hist<<<NE / 256, 256, 0, stream>>>(ei, cnt);
    k_scan1<<<NSB, 256, 0, stream>>>(cnt, offs, bsum);
    k_scan2<<<1, 512, 0, stream>>>(bsum);
    k_scan3<<<NSB, 256, 0, stream>>>(offs, bsum, head);
    k_scatter<<<NE / 256, 256, 0, stream>>>(ei, eattr, short_w, short_b, head, meta);

    for (int i = 0; i < 2; i++) {
        const float* wf = conv_f_w + (size_t)i * 133 * 64;
        const float* wsv = conv_s_w + (size_t)i * 133 * 64;
        const float* bf = conv_f_b + (size_t)i * 64;
        const float* bs = conv_s_b + (size_t)i * 64;
        const float* xin = i ? X1 : X0;
        float* out = i ? (float*)d_out : X1;

        k_wpack<<<8, 256, 0, stream>>>(wf, wsv, Bp);
        k_projm<<<NN / 32, 256, 0, stream>>>(XB, Bp, bf, bs, Pd, Ps);
        k_seg<<<NN / 4, 256, 0, stream>>>(offs, meta, Pd, Ps,
                                          wf + 128 * 64, wsv + 128 * 64, xin, out,
                                          i ? (unsigned short*)nullptr : XB);
    }
}

// Round 7
// 440.611 us; speedup vs baseline: 3.2180x; 1.0228x over previous
//
#include <hip/hip_runtime.h>

#define NN 100000
#define NE 1600000
#define NSB 391  // ceil(NN/256) scan blocks

#define LOG2E 1.4426950408889634f
#define LN2 0.6931471805599453f

typedef short short4v __attribute__((ext_vector_type(4)));
typedef short short8v __attribute__((ext_vector_type(8)));
typedef float f32x4 __attribute__((ext_vector_type(4)));
typedef unsigned u32x4 __attribute__((ext_vector_type(4)));

static __device__ __forceinline__ unsigned f2bf(float x) {
    unsigned b = __float_as_uint(x);
    return (b + 0x7FFFu + ((b >> 16) & 1u)) >> 16;  // RNE bf16 bits
}
static __device__ __forceinline__ float bflo(unsigned u) { return __uint_as_float(u << 16); }
static __device__ __forceinline__ float bfhi(unsigned u) { return __uint_as_float(u & 0xFFFF0000u); }
static __device__ __forceinline__ int imin(int a, int b) { return a < b ? a : b; }
static __device__ __forceinline__ short8v mk8(short4v a, short4v b) {
    short8v r;
    r[0] = a[0]; r[1] = a[1]; r[2] = a[2]; r[3] = a[3];
    r[4] = b[0]; r[5] = b[1]; r[6] = b[2]; r[7] = b[3];
    return r;
}

// One edge's gated-message contribution (log2-domain).
static __device__ __forceinline__ float edge_acc(uint4 m, unsigned ps, float npdf, float pds,
                                                 const float* __restrict__ wfv,
                                                 const float* __restrict__ wsv, float acc) {
    float nzf = npdf + bflo(ps);
    float zsp = pds + bfhi(ps);
    const float e50 = bflo(m.y), e51 = bfhi(m.y);
    const float e52 = bflo(m.z), e53 = bfhi(m.z);
    const float e54 = bflo(m.w);
    nzf = fmaf(e50, wfv[0], nzf);
    nzf = fmaf(e51, wfv[1], nzf);
    nzf = fmaf(e52, wfv[2], nzf);
    nzf = fmaf(e53, wfv[3], nzf);
    nzf = fmaf(e54, wfv[4], nzf);
    zsp = fmaf(e50, wsv[0], zsp);
    zsp = fmaf(e51, wsv[1], zsp);
    zsp = fmaf(e52, wsv[2], zsp);
    zsp = fmaf(e53, wsv[3], zsp);
    zsp = fmaf(e54, wsv[4], zsp);
    const float sig = __builtin_amdgcn_rcpf(1.f + __builtin_amdgcn_exp2f(nzf));
    const float gg = fmaxf(zsp, 0.f) +
                     __builtin_amdgcn_logf(1.f + __builtin_amdgcn_exp2f(-fabsf(zsp)));
    return fmaf(sig, gg, acc);
}

// ---------------------------------------------------------------------------
// Fused: blocks [0,6250): X0 = relu(h @ lin0_w + lin0_b), 16 rows/block
//        blocks [6250,7500): dst histogram, 5 edges/thread (overlaps lin0)
__global__ __launch_bounds__(256) void k_lin0_hist(const float* __restrict__ h,
                                                   const float* __restrict__ w,
                                                   const float* __restrict__ b,
                                                   float* __restrict__ x0,
                                                   unsigned short* __restrict__ xb,
                                                   const int* __restrict__ ei,
                                                   int* __restrict__ cnt) {
    if (blockIdx.x >= 6250) {
        const int base = (blockIdx.x - 6250) * 1280 + threadIdx.x;
#pragma unroll
        for (int j = 0; j < 5; j++) atomicAdd(&cnt[ei[NE + base + j * 256]], 1);
        return;
    }
    __shared__ float wl[64 * 64];
    for (int i = threadIdx.x; i < 64 * 64; i += 256) wl[i] = w[i];
    __syncthreads();
    const int rowbase = blockIdx.x * 16;
    const int col = threadIdx.x & 63;
    const int wv = threadIdx.x >> 6;
    const float bc = b[col];
    for (int r = wv; r < 16; r += 4) {
        const int row = rowbase + r;
        const float* hr = h + (size_t)row * 64;
        float acc = bc;
#pragma unroll
        for (int k = 0; k < 64; k += 4) {
            const float4 hv = *(const float4*)(hr + k);  // wave-uniform -> scalar loads
            acc += hv.x * wl[(k + 0) * 64 + col] + hv.y * wl[(k + 1) * 64 + col] +
                   hv.z * wl[(k + 2) * 64 + col] + hv.w * wl[(k + 3) * 64 + col];
        }
        const float rv = fmaxf(acc, 0.f);
        x0[(size_t)row * 64 + col] = rv;
        xb[(size_t)row * 64 + col] = (unsigned short)f2bf(rv);
    }
}

// ---------------------------------------------------------------------------
__global__ __launch_bounds__(256) void k_scan1(const int* __restrict__ cnt,
                                               int* __restrict__ offs, int* __restrict__ bsum) {
    __shared__ int sm[256];
    const int t = threadIdx.x;
    const int i = blockIdx.x * 256 + t;
    const int v = (i < NN) ? cnt[i] : 0;
    sm[t] = v;
    __syncthreads();
    for (int off = 1; off < 256; off <<= 1) {
        const int x = (t >= off) ? sm[t - off] : 0;
        __syncthreads();
        sm[t] += x;
        __syncthreads();
    }
    if (i < NN) offs[i] = sm[t] - v;
    if (t == 255) bsum[blockIdx.x] = sm[255];
}

__global__ __launch_bounds__(512) void k_scan2(int* __restrict__ bsum) {
    __shared__ int sm[512];
    const int t = threadIdx.x;
    const int v = (t < NSB) ? bsum[t] : 0;
    sm[t] = v;
    __syncthreads();
    for (int off = 1; off < 512; off <<= 1) {
        const int x = (t >= off) ? sm[t - off] : 0;
        __syncthreads();
        sm[t] += x;
        __syncthreads();
    }
    if (t < NSB) bsum[t] = sm[t] - v;
}

__global__ __launch_bounds__(256) void k_scan3(int* __restrict__ offs, const int* __restrict__ bsum,
                                               int* __restrict__ head) {
    const int i = blockIdx.x * 256 + threadIdx.x;
    if (i < NN) {
        const int v = offs[i] + bsum[blockIdx.x];
        offs[i] = v;
        head[i] = v;
    }
    if (i == 0) offs[NN] = NE;
}

// ---------------------------------------------------------------------------
// scatter: meta[pos] = { src, e5 packed bf16 } grouped by dst.
// 5 edges/thread -> 5 independent atomic->store chains in flight.
__global__ __launch_bounds__(256) void k_scatter(const int* __restrict__ ei,
                                                 const float* __restrict__ eattr,
                                                 const float* __restrict__ sw,
                                                 const float* __restrict__ sb,
                                                 int* __restrict__ head,
                                                 uint4* __restrict__ meta) {
    __shared__ float swl[25], sbl[5];
    if (threadIdx.x < 25) swl[threadIdx.x] = sw[threadIdx.x];
    if (threadIdx.x >= 32 && threadIdx.x < 37) sbl[threadIdx.x - 32] = sb[threadIdx.x - 32];
    __syncthreads();
    const int base = blockIdx.x * 1280 + threadIdx.x;
    int s[5], d[5];
    float ea[5][5];
#pragma unroll
    for (int j = 0; j < 5; j++) {
        const int e = base + j * 256;
        s[j] = ei[e];
        d[j] = ei[NE + e];
#pragma unroll
        for (int k = 0; k < 5; k++) ea[j][k] = eattr[(size_t)e * 5 + k];
    }
    int pos[5];
#pragma unroll
    for (int j = 0; j < 5; j++) pos[j] = atomicAdd(&head[d[j]], 1);
#pragma unroll
    for (int j = 0; j < 5; j++) {
        unsigned u5[5];
#pragma unroll
        for (int k = 0; k < 5; k++) {
            float a = sbl[k];
#pragma unroll
            for (int q = 0; q < 5; q++) a += ea[j][q] * swl[q * 5 + k];
            u5[k] = f2bf(fmaxf(a, 0.f));
        }
        uint4 m;
        m.x = (unsigned)s[j];
        m.y = u5[0] | (u5[1] << 16);
        m.z = u5[2] | (u5[3] << 16);
        m.w = u5[4];
        meta[pos[j]] = m;
    }
}

// ---------------------------------------------------------------------------
// Pack BOTH layers' 4 64x64 weight mats into MFMA B-fragment layout, bf16,
// LOG2E-scaled/sign-folded. mat: 0=dstF 1=dstS 2=srcF 3=srcS.
__global__ __launch_bounds__(256) void k_wpack(const float* __restrict__ cfw,
                                               const float* __restrict__ csw,
                                               unsigned short* __restrict__ Bp) {
    const int qq = blockIdx.x * 256 + threadIdx.x;  // 4096 total (2 layers)
    const int layer = qq >> 11;
    const int q = qq & 2047;
    const float* wfL = cfw + (size_t)layer * 133 * 64;
    const float* wsL = csw + (size_t)layer * 133 * 64;
    const int m = q >> 9;
    const int rem = q & 511;
    const int ct = rem >> 7;
    const int kh = (rem >> 6) & 1;
    const int l = rem & 63;
    const float scale = (m & 1) ? LOG2E : -LOG2E;
    const float* src = (m & 1) ? wsL : wfL;
    const int roff = (m >> 1) ? 64 : 0;
    const int n = ct * 16 + (l & 15);
#pragma unroll
    for (int j = 0; j < 8; j++) {
        const int k = kh * 32 + ((j < 4) ? (4 * (l >> 4) + j) : (16 + 4 * (l >> 4) + j - 4));
        Bp[(size_t)qq * 8 + j] = (unsigned short)f2bf(scale * src[(size_t)(roff + k) * 64 + n]);
    }
}

// ---------------------------------------------------------------------------
// MFMA projections, 32 rows per block (each wave: 1 col-tile x 2 row-tiles,
// B-fragments reused across row-tiles).
__global__ __launch_bounds__(256) void k_projm(const unsigned short* __restrict__ xb,
                                               const unsigned short* __restrict__ Bp,
                                               const float* __restrict__ bfv,
                                               const float* __restrict__ bsv,
                                               unsigned* __restrict__ Pd,
                                               unsigned* __restrict__ Ps) {
    __shared__ __align__(16) short xl[32 * 64];
    const int rowbase = blockIdx.x * 32;
    {
        const u32x4* xsrc = (const u32x4*)(xb + (size_t)rowbase * 64);  // 4096 B
        u32x4* xdst = (u32x4*)xl;
        xdst[threadIdx.x] = __builtin_nontemporal_load(&xsrc[threadIdx.x]);
    }
    __syncthreads();
    const int ct = threadIdx.x >> 6;
    const int l = threadIdx.x & 63;
    const int lm = l & 15;
    const int g = l >> 4;
    short8v A[2][2];
#pragma unroll
    for (int rt = 0; rt < 2; rt++) {
        const short* xrow = &xl[(rt * 16 + lm) * 64];
        A[rt][0] = mk8(*(const short4v*)&xrow[g * 4], *(const short4v*)&xrow[16 + g * 4]);
        A[rt][1] = mk8(*(const short4v*)&xrow[32 + g * 4], *(const short4v*)&xrow[48 + g * 4]);
    }
    const short* bp = (const short*)Bp;
    f32x4 acc[4][2];
#pragma unroll
    for (int m = 0; m < 4; m++) {
        const short8v B0 = *(const short8v*)&bp[(((m * 4 + ct) * 2 + 0) * 64 + l) * 8];
        const short8v B1 = *(const short8v*)&bp[(((m * 4 + ct) * 2 + 1) * 64 + l) * 8];
#pragma unroll
        for (int rt = 0; rt < 2; rt++) {
            f32x4 a = {0.f, 0.f, 0.f, 0.f};
            a = __builtin_amdgcn_mfma_f32_16x16x32_bf16(A[rt][0], B0, a, 0, 0, 0);
            a = __builtin_amdgcn_mfma_f32_16x16x32_bf16(A[rt][1], B1, a, 0, 0, 0);
            acc[m][rt] = a;
        }
    }
    const int col = ct * 16 + lm;
    const float bfb = -LOG2E * bfv[col];
    const float bsb = LOG2E * bsv[col];
#pragma unroll
    for (int rt = 0; rt < 2; rt++) {
#pragma unroll
        for (int reg = 0; reg < 4; reg++) {
            const int rowg = rowbase + rt * 16 + g * 4 + reg;
            Pd[(size_t)rowg * 64 + col] =
                f2bf(acc[0][rt][reg] + bfb) | (f2bf(acc[1][rt][reg] + bsb) << 16);
            Ps[(size_t)rowg * 64 + col] =
                f2bf(acc[2][rt][reg]) | (f2bf(acc[3][rt][reg]) << 16);
        }
    }
}

// ---------------------------------------------------------------------------
// Segment aggregation: one wave per dst node, edges pre-sorted by dst.
// 4-wide batched pipeline: meta prefetched 2 batches ahead (scalar loads),
// 4 independent Ps gathers in flight; peeled predicated last batch.
__global__ __launch_bounds__(256) void k_seg(const int* __restrict__ offs,
                                             const uint4* __restrict__ meta,
                                             const unsigned* __restrict__ Pd,
                                             const unsigned* __restrict__ Ps,
                                             const float* __restrict__ wfE,
                                             const float* __restrict__ wsE,
                                             const float* __restrict__ xin,
                                             float* __restrict__ out,
                                             unsigned short* __restrict__ xbout) {
    __shared__ float wfl[320], wsl[320];
    for (int i = threadIdx.x; i < 320; i += 256) {
        wfl[i] = -LOG2E * wfE[i];
        wsl[i] = LOG2E * wsE[i];
    }
    __syncthreads();
    const int n = blockIdx.x * 4 + (threadIdx.x >> 6);
    const int lane = threadIdx.x & 63;
    const int start = __builtin_amdgcn_readfirstlane(offs[n]);
    const int end = __builtin_amdgcn_readfirstlane(offs[n + 1]);
    const unsigned pd = __builtin_nontemporal_load(&Pd[(size_t)n * 64 + lane]);
    const float npdf = bflo(pd);
    const float pds = bfhi(pd);
    float wfv[5], wsv[5];
#pragma unroll
    for (int k = 0; k < 5; k++) {
        wfv[k] = wfl[k * 64 + lane];
        wsv[k] = wsl[k * 64 + lane];
    }
    const float xv = __builtin_nontemporal_load(&xin[(size_t)n * 64 + lane]);
    float acc = 0.f;
    const int cnt = end - start;
    if (cnt > 0) {
        const int last = end - 1;
        const int nbF = (cnt + 3) >> 2;
        uint4 M0[4], M1[4];
        unsigned PS0[4];
#pragma unroll
        for (int j = 0; j < 4; j++) M0[j] = meta[imin(start + j, last)];
#pragma unroll
        for (int j = 0; j < 4; j++) M1[j] = meta[imin(start + 4 + j, last)];
#pragma unroll
        for (int j = 0; j < 4; j++) PS0[j] = Ps[(size_t)M0[j].x * 64 + lane];
        for (int b = 0; b < nbF - 1; b++) {
            const int base2 = start + (b + 2) * 4;
            uint4 M2[4];
            unsigned PS1[4];
#pragma unroll
            for (int j = 0; j < 4; j++) M2[j] = meta[imin(base2 + j, last)];
#pragma unroll
            for (int j = 0; j < 4; j++) PS1[j] = Ps[(size_t)M1[j].x * 64 + lane];
#pragma unroll
            for (int j = 0; j < 4; j++) acc = edge_acc(M0[j], PS0[j], npdf, pds, wfv, wsv, acc);
#pragma unroll
            for (int j = 0; j < 4; j++) {
                M0[j] = M1[j];
                M1[j] = M2[j];
                PS0[j] = PS1[j];
            }
        }
        const int lb = start + (nbF - 1) * 4;
#pragma unroll
        for (int j = 0; j < 4; j++)
            if (lb + j < end) acc = edge_acc(M0[j], PS0[j], npdf, pds, wfv, wsv, acc);
    }
    const float res = fmaxf(fmaf(acc, LN2, xv), 0.f);
    if (xbout) {
        out[(size_t)n * 64 + lane] = res;  // X1: re-read next layer, keep cached
        xbout[(size_t)n * 64 + lane] = (unsigned short)f2bf(res);
    } else {
        __builtin_nontemporal_store(res, &out[(size_t)n * 64 + lane]);  // final output
    }
}

// ---------------------------------------------------------------------------
extern "C" void kernel_launch(void* const* d_in, const int* in_sizes, int n_in,
                              void* d_out, int out_size, void* d_ws, size_t ws_size,
                              hipStream_t stream) {
    const float* h = (const float*)d_in[0];
    const int* ei = (const int*)d_in[1];
    const float* eattr = (const float*)d_in[3];
    const float* lin0_w = (const float*)d_in[5];
    const float* lin0_b = (const float*)d_in[6];
    const float* short_w = (const float*)d_in[7];
    const float* short_b = (const float*)d_in[8];
    const float* conv_f_w = (const float*)d_in[9];
    const float* conv_f_b = (const float*)d_in[10];
    const float* conv_s_w = (const float*)d_in[11];
    const float* conv_s_b = (const float*)d_in[12];

    char* ws = (char*)d_ws;
    uint4* meta = (uint4*)ws;                             // [NE] 16B, 25.6 MB
    float* X0 = (float*)(ws + (size_t)NE * 16);           // [NN*64] f32
    float* X1 = X0 + (size_t)NN * 64;                     // [NN*64] f32
    unsigned* Pd = (unsigned*)(X1 + (size_t)NN * 64);     // [NN*64] u32
    unsigned* Ps = Pd + (size_t)NN * 64;                  // [NN*64] u32
    unsigned short* XB = (unsigned short*)(Ps + (size_t)NN * 64);  // [NN*64] bf16
    unsigned short* Bp = XB + (size_t)NN * 64;            // [2][16384] packed weights
    int* cnt = (int*)(Bp + 32768);                        // [NN]
    int* offs = cnt + NN;                                 // [NN+1]
    int* head = offs + NN + 1;                            // [NN]
    int* bsum = head + NN;                                // [NSB]

    hipMemsetAsync(cnt, 0, (size_t)NN * 4, stream);
    k_lin0_hist<<<6250 + 1250, 256, 0, stream>>>(h, lin0_w, lin0_b, X0, XB, ei, cnt);
    k_scan1<<<NSB, 256, 0, stream>>>(cnt, offs, bsum);
    k_scan2<<<1, 512, 0, stream>>>(bsum);
    k_scan3<<<NSB, 256, 0, stream>>>(offs, bsum, head);
    k_scatter<<<1250, 256, 0, stream>>>(ei, eattr, short_w, short_b, head, meta);
    k_wpack<<<16, 256, 0, stream>>>(conv_f_w, conv_s_w, Bp);

    for (int i = 0; i < 2; i++) {
        const float* wf = conv_f_w + (size_t)i * 133 * 64;
        const float* wsv = conv_s_w + (size_t)i * 133 * 64;
        const float* bf = conv_f_b + (size_t)i * 64;
        const float* bs = conv_s_b + (size_t)i * 64;
        const float* xin = i ? X1 : X0;
        float* out = i ? (float*)d_out : X1;

        k_projm<<<NN / 32, 256, 0, stream>>>(XB, Bp + (size_t)i * 16384, bf, bs, Pd, Ps);
        k_seg<<<NN / 4, 256, 0, stream>>>(offs, meta, Pd, Ps,
                                          wf + 128 * 64, wsv + 128 * 64, xin, out,
                                          i ? (unsigned short*)nullptr : XB);
    }
}

// Round 8
// 395.125 us; speedup vs baseline: 3.5885x; 1.1151x over previous
//
#include <hip/hip_runtime.h>

#define NN 100000
#define NE 1600000
#define NSB 391  // ceil(NN/256) scan blocks

#define LOG2E 1.4426950408889634f
#define LN2 0.6931471805599453f

typedef short short4v __attribute__((ext_vector_type(4)));
typedef short short8v __attribute__((ext_vector_type(8)));
typedef float f32x4 __attribute__((ext_vector_type(4)));
typedef unsigned u32x4 __attribute__((ext_vector_type(4)));

static __device__ __forceinline__ unsigned f2bf(float x) {
    unsigned b = __float_as_uint(x);
    return (b + 0x7FFFu + ((b >> 16) & 1u)) >> 16;  // RNE bf16 bits
}
static __device__ __forceinline__ float bflo(unsigned u) { return __uint_as_float(u << 16); }
static __device__ __forceinline__ float bfhi(unsigned u) { return __uint_as_float(u & 0xFFFF0000u); }
static __device__ __forceinline__ int imin(int a, int b) { return a < b ? a : b; }
static __device__ __forceinline__ short8v mk8(short4v a, short4v b) {
    short8v r;
    r[0] = a[0]; r[1] = a[1]; r[2] = a[2]; r[3] = a[3];
    r[4] = b[0]; r[5] = b[1]; r[6] = b[2]; r[7] = b[3];
    return r;
}

// One edge's gated-message contribution (log2-domain).
static __device__ __forceinline__ float edge_acc(uint4 m, unsigned ps, float npdf, float pds,
                                                 const float* __restrict__ wfv,
                                                 const float* __restrict__ wsv, float acc) {
    float nzf = npdf + bflo(ps);
    float zsp = pds + bfhi(ps);
    const float e50 = bflo(m.y), e51 = bfhi(m.y);
    const float e52 = bflo(m.z), e53 = bfhi(m.z);
    const float e54 = bflo(m.w);
    nzf = fmaf(e50, wfv[0], nzf);
    nzf = fmaf(e51, wfv[1], nzf);
    nzf = fmaf(e52, wfv[2], nzf);
    nzf = fmaf(e53, wfv[3], nzf);
    nzf = fmaf(e54, wfv[4], nzf);
    zsp = fmaf(e50, wsv[0], zsp);
    zsp = fmaf(e51, wsv[1], zsp);
    zsp = fmaf(e52, wsv[2], zsp);
    zsp = fmaf(e53, wsv[3], zsp);
    zsp = fmaf(e54, wsv[4], zsp);
    const float sig = __builtin_amdgcn_rcpf(1.f + __builtin_amdgcn_exp2f(nzf));
    const float gg = fmaxf(zsp, 0.f) +
                     __builtin_amdgcn_logf(1.f + __builtin_amdgcn_exp2f(-fabsf(zsp)));
    return fmaf(sig, gg, acc);
}

// ---------------------------------------------------------------------------
// Pack into MFMA B-fragment layout:
//   qq in [0,4096): 2 conv layers x 4 mats (0=dstF 1=dstS 2=srcF 3=srcS),
//                   LOG2E-scaled/sign-folded
//   qq in [4096,4608): lin0_w, unscaled
__global__ __launch_bounds__(256) void k_wpack(const float* __restrict__ cfw,
                                               const float* __restrict__ csw,
                                               const float* __restrict__ l0w,
                                               unsigned short* __restrict__ Bp) {
    const int qq = blockIdx.x * 256 + threadIdx.x;  // 4608 total
    const float* src;
    float scale;
    int roff, ct, kh, l;
    if (qq < 4096) {
        const int layer = qq >> 11;
        const int q = qq & 2047;
        const int m = q >> 9;
        const int rem = q & 511;
        ct = rem >> 7;
        kh = (rem >> 6) & 1;
        l = rem & 63;
        scale = (m & 1) ? LOG2E : -LOG2E;
        src = ((m & 1) ? csw : cfw) + (size_t)layer * 133 * 64;
        roff = (m >> 1) ? 64 : 0;
    } else {
        const int p = qq - 4096;
        ct = p >> 7;
        kh = (p >> 6) & 1;
        l = p & 63;
        scale = 1.f;
        src = l0w;
        roff = 0;
    }
    const int n = ct * 16 + (l & 15);
#pragma unroll
    for (int j = 0; j < 8; j++) {
        const int k = kh * 32 + ((j < 4) ? (4 * (l >> 4) + j) : (16 + 4 * (l >> 4) + j - 4));
        Bp[(size_t)qq * 8 + j] = (unsigned short)f2bf(scale * src[(size_t)(roff + k) * 64 + n]);
    }
}

// ---------------------------------------------------------------------------
// Fused: blocks [0,1250):    dst histogram, 5 edges/thread (runs FIRST,
//                            latency-bound, overlaps with lin0 blocks)
//        blocks [1250,4375): X0 = relu(h @ lin0_w + b) via MFMA, 32 rows/block
__global__ __launch_bounds__(256) void k_lin0m_hist(const float* __restrict__ h,
                                                    const unsigned short* __restrict__ Bp0,
                                                    const float* __restrict__ b,
                                                    float* __restrict__ x0,
                                                    unsigned short* __restrict__ xb,
                                                    const int* __restrict__ ei,
                                                    int* __restrict__ cnt) {
    __shared__ __align__(16) short xl[32 * 64];
    if (blockIdx.x < 1250) {
        const int base = blockIdx.x * 1280 + threadIdx.x;
#pragma unroll
        for (int j = 0; j < 5; j++) atomicAdd(&cnt[ei[NE + base + j * 256]], 1);
        return;
    }
    const int rowbase = (blockIdx.x - 1250) * 32;
    // stage 32x64 h-tile as bf16 (coalesced float4 loads)
    {
        const float4* hs = (const float4*)(h + (size_t)rowbase * 64);
#pragma unroll
        for (int it = 0; it < 2; it++) {
            const float4 v = hs[threadIdx.x + it * 256];
            short4v sv;
            sv[0] = (short)f2bf(v.x);
            sv[1] = (short)f2bf(v.y);
            sv[2] = (short)f2bf(v.z);
            sv[3] = (short)f2bf(v.w);
            *(short4v*)&xl[(threadIdx.x + it * 256) * 4] = sv;
        }
    }
    __syncthreads();
    const int ct = threadIdx.x >> 6;
    const int l = threadIdx.x & 63;
    const int lm = l & 15;
    const int g = l >> 4;
    short8v A[2][2];
#pragma unroll
    for (int rt = 0; rt < 2; rt++) {
        const short* xrow = &xl[(rt * 16 + lm) * 64];
        A[rt][0] = mk8(*(const short4v*)&xrow[g * 4], *(const short4v*)&xrow[16 + g * 4]);
        A[rt][1] = mk8(*(const short4v*)&xrow[32 + g * 4], *(const short4v*)&xrow[48 + g * 4]);
    }
    const short* bp = (const short*)Bp0;
    const short8v B0 = *(const short8v*)&bp[((ct * 2 + 0) * 64 + l) * 8];
    const short8v B1 = *(const short8v*)&bp[((ct * 2 + 1) * 64 + l) * 8];
    const int col = ct * 16 + lm;
    const float bc = b[col];
#pragma unroll
    for (int rt = 0; rt < 2; rt++) {
        f32x4 a = {0.f, 0.f, 0.f, 0.f};
        a = __builtin_amdgcn_mfma_f32_16x16x32_bf16(A[rt][0], B0, a, 0, 0, 0);
        a = __builtin_amdgcn_mfma_f32_16x16x32_bf16(A[rt][1], B1, a, 0, 0, 0);
#pragma unroll
        for (int reg = 0; reg < 4; reg++) {
            const int rowg = rowbase + rt * 16 + g * 4 + reg;
            const float r = fmaxf(a[reg] + bc, 0.f);
            x0[(size_t)rowg * 64 + col] = r;
            xb[(size_t)rowg * 64 + col] = (unsigned short)f2bf(r);
        }
    }
}

// ---------------------------------------------------------------------------
__global__ __launch_bounds__(256) void k_scan1(const int* __restrict__ cnt,
                                               int* __restrict__ offs, int* __restrict__ bsum) {
    __shared__ int sm[256];
    const int t = threadIdx.x;
    const int i = blockIdx.x * 256 + t;
    const int v = (i < NN) ? cnt[i] : 0;
    sm[t] = v;
    __syncthreads();
    for (int off = 1; off < 256; off <<= 1) {
        const int x = (t >= off) ? sm[t - off] : 0;
        __syncthreads();
        sm[t] += x;
        __syncthreads();
    }
    if (i < NN) offs[i] = sm[t] - v;
    if (t == 255) bsum[blockIdx.x] = sm[255];
}

__global__ __launch_bounds__(512) void k_scan2(int* __restrict__ bsum) {
    __shared__ int sm[512];
    const int t = threadIdx.x;
    const int v = (t < NSB) ? bsum[t] : 0;
    sm[t] = v;
    __syncthreads();
    for (int off = 1; off < 512; off <<= 1) {
        const int x = (t >= off) ? sm[t - off] : 0;
        __syncthreads();
        sm[t] += x;
        __syncthreads();
    }
    if (t < NSB) bsum[t] = sm[t] - v;
}

__global__ __launch_bounds__(256) void k_scan3(int* __restrict__ offs, const int* __restrict__ bsum,
                                               int* __restrict__ head) {
    const int i = blockIdx.x * 256 + threadIdx.x;
    if (i < NN) {
        const int v = offs[i] + bsum[blockIdx.x];
        offs[i] = v;
        head[i] = v;
    }
    if (i == 0) offs[NN] = NE;
}

// ---------------------------------------------------------------------------
// scatter: meta[pos] = { src, e5 packed bf16 } grouped by dst.
// 5 edges/thread -> 5 independent atomic->store chains in flight.
__global__ __launch_bounds__(256) void k_scatter(const int* __restrict__ ei,
                                                 const float* __restrict__ eattr,
                                                 const float* __restrict__ sw,
                                                 const float* __restrict__ sb,
                                                 int* __restrict__ head,
                                                 uint4* __restrict__ meta) {
    __shared__ float swl[25], sbl[5];
    if (threadIdx.x < 25) swl[threadIdx.x] = sw[threadIdx.x];
    if (threadIdx.x >= 32 && threadIdx.x < 37) sbl[threadIdx.x - 32] = sb[threadIdx.x - 32];
    __syncthreads();
    const int base = blockIdx.x * 1280 + threadIdx.x;
    int s[5], d[5];
    float ea[5][5];
#pragma unroll
    for (int j = 0; j < 5; j++) {
        const int e = base + j * 256;
        s[j] = ei[e];
        d[j] = ei[NE + e];
#pragma unroll
        for (int k = 0; k < 5; k++) ea[j][k] = eattr[(size_t)e * 5 + k];
    }
    int pos[5];
#pragma unroll
    for (int j = 0; j < 5; j++) pos[j] = atomicAdd(&head[d[j]], 1);
#pragma unroll
    for (int j = 0; j < 5; j++) {
        unsigned u5[5];
#pragma unroll
        for (int k = 0; k < 5; k++) {
            float a = sbl[k];
#pragma unroll
            for (int q = 0; q < 5; q++) a += ea[j][q] * swl[q * 5 + k];
            u5[k] = f2bf(fmaxf(a, 0.f));
        }
        uint4 m;
        m.x = (unsigned)s[j];
        m.y = u5[0] | (u5[1] << 16);
        m.z = u5[2] | (u5[3] << 16);
        m.w = u5[4];
        meta[pos[j]] = m;
    }
}

// ---------------------------------------------------------------------------
// MFMA projections, 32 rows per block (each wave: 1 col-tile x 2 row-tiles,
// B-fragments reused across row-tiles).
__global__ __launch_bounds__(256) void k_projm(const unsigned short* __restrict__ xb,
                                               const unsigned short* __restrict__ Bp,
                                               const float* __restrict__ bfv,
                                               const float* __restrict__ bsv,
                                               unsigned* __restrict__ Pd,
                                               unsigned* __restrict__ Ps) {
    __shared__ __align__(16) short xl[32 * 64];
    const int rowbase = blockIdx.x * 32;
    {
        const u32x4* xsrc = (const u32x4*)(xb + (size_t)rowbase * 64);  // 4096 B
        u32x4* xdst = (u32x4*)xl;
        xdst[threadIdx.x] = __builtin_nontemporal_load(&xsrc[threadIdx.x]);
    }
    __syncthreads();
    const int ct = threadIdx.x >> 6;
    const int l = threadIdx.x & 63;
    const int lm = l & 15;
    const int g = l >> 4;
    short8v A[2][2];
#pragma unroll
    for (int rt = 0; rt < 2; rt++) {
        const short* xrow = &xl[(rt * 16 + lm) * 64];
        A[rt][0] = mk8(*(const short4v*)&xrow[g * 4], *(const short4v*)&xrow[16 + g * 4]);
        A[rt][1] = mk8(*(const short4v*)&xrow[32 + g * 4], *(const short4v*)&xrow[48 + g * 4]);
    }
    const short* bp = (const short*)Bp;
    f32x4 acc[4][2];
#pragma unroll
    for (int m = 0; m < 4; m++) {
        const short8v B0 = *(const short8v*)&bp[(((m * 4 + ct) * 2 + 0) * 64 + l) * 8];
        const short8v B1 = *(const short8v*)&bp[(((m * 4 + ct) * 2 + 1) * 64 + l) * 8];
#pragma unroll
        for (int rt = 0; rt < 2; rt++) {
            f32x4 a = {0.f, 0.f, 0.f, 0.f};
            a = __builtin_amdgcn_mfma_f32_16x16x32_bf16(A[rt][0], B0, a, 0, 0, 0);
            a = __builtin_amdgcn_mfma_f32_16x16x32_bf16(A[rt][1], B1, a, 0, 0, 0);
            acc[m][rt] = a;
        }
    }
    const int col = ct * 16 + lm;
    const float bfb = -LOG2E * bfv[col];
    const float bsb = LOG2E * bsv[col];
#pragma unroll
    for (int rt = 0; rt < 2; rt++) {
#pragma unroll
        for (int reg = 0; reg < 4; reg++) {
            const int rowg = rowbase + rt * 16 + g * 4 + reg;
            Pd[(size_t)rowg * 64 + col] =
                f2bf(acc[0][rt][reg] + bfb) | (f2bf(acc[1][rt][reg] + bsb) << 16);
            Ps[(size_t)rowg * 64 + col] =
                f2bf(acc[2][rt][reg]) | (f2bf(acc[3][rt][reg]) << 16);
        }
    }
}

// ---------------------------------------------------------------------------
// Segment aggregation: one wave per dst node, edges pre-sorted by dst.
// 4-wide batched pipeline: meta prefetched 2 batches ahead (scalar loads),
// 4 independent Ps gathers in flight; peeled predicated last batch.
__global__ __launch_bounds__(256) void k_seg(const int* __restrict__ offs,
                                             const uint4* __restrict__ meta,
                                             const unsigned* __restrict__ Pd,
                                             const unsigned* __restrict__ Ps,
                                             const float* __restrict__ wfE,
                                             const float* __restrict__ wsE,
                                             const float* __restrict__ xin,
                                             float* __restrict__ out,
                                             unsigned short* __restrict__ xbout) {
    __shared__ float wfl[320], wsl[320];
    for (int i = threadIdx.x; i < 320; i += 256) {
        wfl[i] = -LOG2E * wfE[i];
        wsl[i] = LOG2E * wsE[i];
    }
    __syncthreads();
    const int n = blockIdx.x * 4 + (threadIdx.x >> 6);
    const int lane = threadIdx.x & 63;
    const int start = __builtin_amdgcn_readfirstlane(offs[n]);
    const int end = __builtin_amdgcn_readfirstlane(offs[n + 1]);
    const unsigned pd = __builtin_nontemporal_load(&Pd[(size_t)n * 64 + lane]);
    const float npdf = bflo(pd);
    const float pds = bfhi(pd);
    float wfv[5], wsv[5];
#pragma unroll
    for (int k = 0; k < 5; k++) {
        wfv[k] = wfl[k * 64 + lane];
        wsv[k] = wsl[k * 64 + lane];
    }
    const float xv = __builtin_nontemporal_load(&xin[(size_t)n * 64 + lane]);
    float acc = 0.f;
    const int cnt = end - start;
    if (cnt > 0) {
        const int last = end - 1;
        const int nbF = (cnt + 3) >> 2;
        uint4 M0[4], M1[4];
        unsigned PS0[4];
#pragma unroll
        for (int j = 0; j < 4; j++) M0[j] = meta[imin(start + j, last)];
#pragma unroll
        for (int j = 0; j < 4; j++) M1[j] = meta[imin(start + 4 + j, last)];
#pragma unroll
        for (int j = 0; j < 4; j++) PS0[j] = Ps[(size_t)M0[j].x * 64 + lane];
        for (int b = 0; b < nbF - 1; b++) {
            const int base2 = start + (b + 2) * 4;
            uint4 M2[4];
            unsigned PS1[4];
#pragma unroll
            for (int j = 0; j < 4; j++) M2[j] = meta[imin(base2 + j, last)];
#pragma unroll
            for (int j = 0; j < 4; j++) PS1[j] = Ps[(size_t)M1[j].x * 64 + lane];
#pragma unroll
            for (int j = 0; j < 4; j++) acc = edge_acc(M0[j], PS0[j], npdf, pds, wfv, wsv, acc);
#pragma unroll
            for (int j = 0; j < 4; j++) {
                M0[j] = M1[j];
                M1[j] = M2[j];
                PS0[j] = PS1[j];
            }
        }
        const int lb = start + (nbF - 1) * 4;
#pragma unroll
        for (int j = 0; j < 4; j++)
            if (lb + j < end) acc = edge_acc(M0[j], PS0[j], npdf, pds, wfv, wsv, acc);
    }
    const float res = fmaxf(fmaf(acc, LN2, xv), 0.f);
    if (xbout) {
        out[(size_t)n * 64 + lane] = res;  // X1: re-read next layer, keep cached
        xbout[(size_t)n * 64 + lane] = (unsigned short)f2bf(res);
    } else {
        __builtin_nontemporal_store(res, &out[(size_t)n * 64 + lane]);  // final output
    }
}

// ---------------------------------------------------------------------------
extern "C" void kernel_launch(void* const* d_in, const int* in_sizes, int n_in,
                              void* d_out, int out_size, void* d_ws, size_t ws_size,
                              hipStream_t stream) {
    const float* h = (const float*)d_in[0];
    const int* ei = (const int*)d_in[1];
    const float* eattr = (const float*)d_in[3];
    const float* lin0_w = (const float*)d_in[5];
    const float* lin0_b = (const float*)d_in[6];
    const float* short_w = (const float*)d_in[7];
    const float* short_b = (const float*)d_in[8];
    const float* conv_f_w = (const float*)d_in[9];
    const float* conv_f_b = (const float*)d_in[10];
    const float* conv_s_w = (const float*)d_in[11];
    const float* conv_s_b = (const float*)d_in[12];

    char* ws = (char*)d_ws;
    uint4* meta = (uint4*)ws;                             // [NE] 16B, 25.6 MB
    float* X0 = (float*)(ws + (size_t)NE * 16);           // [NN*64] f32
    float* X1 = X0 + (size_t)NN * 64;                     // [NN*64] f32
    unsigned* Pd = (unsigned*)(X1 + (size_t)NN * 64);     // [NN*64] u32
    unsigned* Ps = Pd + (size_t)NN * 64;                  // [NN*64] u32
    unsigned short* XB = (unsigned short*)(Ps + (size_t)NN * 64);  // [NN*64] bf16
    unsigned short* Bp = XB + (size_t)NN * 64;            // [2][16384]+[4096] packed weights
    int* cnt = (int*)(Bp + 36864);                        // [NN]
    int* offs = cnt + NN;                                 // [NN+1]
    int* head = offs + NN + 1;                            // [NN]
    int* bsum = head + NN;                                // [NSB]

    hipMemsetAsync(cnt, 0, (size_t)NN * 4, stream);
    k_wpack<<<18, 256, 0, stream>>>(conv_f_w, conv_s_w, lin0_w, Bp);
    k_lin0m_hist<<<1250 + 3125, 256, 0, stream>>>(h, Bp + 32768, lin0_b, X0, XB, ei, cnt);
    k_scan1<<<NSB, 256, 0, stream>>>(cnt, offs, bsum);
    k_scan2<<<1, 512, 0, stream>>>(bsum);
    k_scan3<<<NSB, 256, 0, stream>>>(offs, bsum, head);
    k_scatter<<<1250, 256, 0, stream>>>(ei, eattr, short_w, short_b, head, meta);

    for (int i = 0; i < 2; i++) {
        const float* wf = conv_f_w + (size_t)i * 133 * 64;
        const float* wsv = conv_s_w + (size_t)i * 133 * 64;
        const float* bf = conv_f_b + (size_t)i * 64;
        const float* bs = conv_s_b + (size_t)i * 64;
        const float* xin = i ? X1 : X0;
        float* out = i ? (float*)d_out : X1;

        k_projm<<<NN / 32, 256, 0, stream>>>(XB, Bp + (size_t)i * 16384, bf, bs, Pd, Ps);
        k_seg<<<NN / 4, 256, 0, stream>>>(offs, meta, Pd, Ps,
                                          wf + 128 * 64, wsv + 128 * 64, xin, out,
                                          i ? (unsigned short*)nullptr : XB);
    }
}

// Round 9
// 359.643 us; speedup vs baseline: 3.9425x; 1.0987x over previous
//
#include <hip/hip_runtime.h>

#define NN 100000
#define NE 1600000
#define NSB 391  // ceil(NN/256) scan blocks

#define LOG2E 1.4426950408889634f
#define LN2 0.6931471805599453f

typedef short short4v __attribute__((ext_vector_type(4)));
typedef short short8v __attribute__((ext_vector_type(8)));
typedef float f32x4 __attribute__((ext_vector_type(4)));
typedef unsigned u32x4 __attribute__((ext_vector_type(4)));

static __device__ __forceinline__ unsigned f2bf(float x) {
    unsigned b = __float_as_uint(x);
    return (b + 0x7FFFu + ((b >> 16) & 1u)) >> 16;  // RNE bf16 bits
}
static __device__ __forceinline__ float bflo(unsigned u) { return __uint_as_float(u << 16); }
static __device__ __forceinline__ float bfhi(unsigned u) { return __uint_as_float(u & 0xFFFF0000u); }
static __device__ __forceinline__ int imin(int a, int b) { return a < b ? a : b; }
static __device__ __forceinline__ short8v mk8(short4v a, short4v b) {
    short8v r;
    r[0] = a[0]; r[1] = a[1]; r[2] = a[2]; r[3] = a[3];
    r[4] = b[0]; r[5] = b[1]; r[6] = b[2]; r[7] = b[3];
    return r;
}

// One edge's gated-message contribution (log2-domain).
static __device__ __forceinline__ float edge_acc(uint4 m, unsigned ps, float npdf, float pds,
                                                 const float* __restrict__ wfv,
                                                 const float* __restrict__ wsv, float acc) {
    float nzf = npdf + bflo(ps);
    float zsp = pds + bfhi(ps);
    const float e50 = bflo(m.y), e51 = bfhi(m.y);
    const float e52 = bflo(m.z), e53 = bfhi(m.z);
    const float e54 = bflo(m.w);
    nzf = fmaf(e50, wfv[0], nzf);
    nzf = fmaf(e51, wfv[1], nzf);
    nzf = fmaf(e52, wfv[2], nzf);
    nzf = fmaf(e53, wfv[3], nzf);
    nzf = fmaf(e54, wfv[4], nzf);
    zsp = fmaf(e50, wsv[0], zsp);
    zsp = fmaf(e51, wsv[1], zsp);
    zsp = fmaf(e52, wsv[2], zsp);
    zsp = fmaf(e53, wsv[3], zsp);
    zsp = fmaf(e54, wsv[4], zsp);
    const float sig = __builtin_amdgcn_rcpf(1.f + __builtin_amdgcn_exp2f(nzf));
    const float gg = fmaxf(zsp, 0.f) +
                     __builtin_amdgcn_logf(1.f + __builtin_amdgcn_exp2f(-fabsf(zsp)));
    return fmaf(sig, gg, acc);
}

// ---------------------------------------------------------------------------
// Pack into MFMA B-fragment layout:
//   qq in [0,4096): 2 conv layers x 4 mats (0=dstF 1=dstS 2=srcF 3=srcS),
//                   LOG2E-scaled/sign-folded
//   qq in [4096,4608): lin0_w, unscaled
__global__ __launch_bounds__(256) void k_wpack(const float* __restrict__ cfw,
                                               const float* __restrict__ csw,
                                               const float* __restrict__ l0w,
                                               unsigned short* __restrict__ Bp) {
    const int qq = blockIdx.x * 256 + threadIdx.x;  // 4608 total
    const float* src;
    float scale;
    int roff, ct, kh, l;
    if (qq < 4096) {
        const int layer = qq >> 11;
        const int q = qq & 2047;
        const int m = q >> 9;
        const int rem = q & 511;
        ct = rem >> 7;
        kh = (rem >> 6) & 1;
        l = rem & 63;
        scale = (m & 1) ? LOG2E : -LOG2E;
        src = ((m & 1) ? csw : cfw) + (size_t)layer * 133 * 64;
        roff = (m >> 1) ? 64 : 0;
    } else {
        const int p = qq - 4096;
        ct = p >> 7;
        kh = (p >> 6) & 1;
        l = p & 63;
        scale = 1.f;
        src = l0w;
        roff = 0;
    }
    const int n = ct * 16 + (l & 15);
#pragma unroll
    for (int j = 0; j < 8; j++) {
        const int k = kh * 32 + ((j < 4) ? (4 * (l >> 4) + j) : (16 + 4 * (l >> 4) + j - 4));
        Bp[(size_t)qq * 8 + j] = (unsigned short)f2bf(scale * src[(size_t)(roff + k) * 64 + n]);
    }
}

// ---------------------------------------------------------------------------
// Fused: blocks [0,1250):    dst histogram + per-edge rank (5 edges/thread;
//                            latency-bound, overlaps with lin0 MFMA blocks)
//        blocks [1250,4375): X0 = relu(h @ lin0_w + b) via MFMA, 32 rows/block
__global__ __launch_bounds__(256) void k_lin0m_hist(const float* __restrict__ h,
                                                    const unsigned short* __restrict__ Bp0,
                                                    const float* __restrict__ b,
                                                    float* __restrict__ x0,
                                                    unsigned short* __restrict__ xb,
                                                    const int* __restrict__ ei,
                                                    int* __restrict__ cnt,
                                                    int* __restrict__ rank) {
    __shared__ __align__(16) short xl[32 * 64];
    if (blockIdx.x < 1250) {
        const int base = blockIdx.x * 1280 + threadIdx.x;
        int r[5];
#pragma unroll
        for (int j = 0; j < 5; j++) r[j] = atomicAdd(&cnt[ei[NE + base + j * 256]], 1);
#pragma unroll
        for (int j = 0; j < 5; j++) rank[base + j * 256] = r[j];
        return;
    }
    const int rowbase = (blockIdx.x - 1250) * 32;
    // stage 32x64 h-tile as bf16 (coalesced float4 loads)
    {
        const float4* hs = (const float4*)(h + (size_t)rowbase * 64);
#pragma unroll
        for (int it = 0; it < 2; it++) {
            const float4 v = hs[threadIdx.x + it * 256];
            short4v sv;
            sv[0] = (short)f2bf(v.x);
            sv[1] = (short)f2bf(v.y);
            sv[2] = (short)f2bf(v.z);
            sv[3] = (short)f2bf(v.w);
            *(short4v*)&xl[(threadIdx.x + it * 256) * 4] = sv;
        }
    }
    __syncthreads();
    const int ct = threadIdx.x >> 6;
    const int l = threadIdx.x & 63;
    const int lm = l & 15;
    const int g = l >> 4;
    short8v A[2][2];
#pragma unroll
    for (int rt = 0; rt < 2; rt++) {
        const short* xrow = &xl[(rt * 16 + lm) * 64];
        A[rt][0] = mk8(*(const short4v*)&xrow[g * 4], *(const short4v*)&xrow[16 + g * 4]);
        A[rt][1] = mk8(*(const short4v*)&xrow[32 + g * 4], *(const short4v*)&xrow[48 + g * 4]);
    }
    const short* bp = (const short*)Bp0;
    const short8v B0 = *(const short8v*)&bp[((ct * 2 + 0) * 64 + l) * 8];
    const short8v B1 = *(const short8v*)&bp[((ct * 2 + 1) * 64 + l) * 8];
    const int col = ct * 16 + lm;
    const float bc = b[col];
#pragma unroll
    for (int rt = 0; rt < 2; rt++) {
        f32x4 a = {0.f, 0.f, 0.f, 0.f};
        a = __builtin_amdgcn_mfma_f32_16x16x32_bf16(A[rt][0], B0, a, 0, 0, 0);
        a = __builtin_amdgcn_mfma_f32_16x16x32_bf16(A[rt][1], B1, a, 0, 0, 0);
#pragma unroll
        for (int reg = 0; reg < 4; reg++) {
            const int rowg = rowbase + rt * 16 + g * 4 + reg;
            const float r = fmaxf(a[reg] + bc, 0.f);
            x0[(size_t)rowg * 64 + col] = r;
            xb[(size_t)rowg * 64 + col] = (unsigned short)f2bf(r);
        }
    }
}

// ---------------------------------------------------------------------------
__global__ __launch_bounds__(256) void k_scan1(const int* __restrict__ cnt,
                                               int* __restrict__ offs, int* __restrict__ bsum) {
    __shared__ int sm[256];
    const int t = threadIdx.x;
    const int i = blockIdx.x * 256 + t;
    const int v = (i < NN) ? cnt[i] : 0;
    sm[t] = v;
    __syncthreads();
    for (int off = 1; off < 256; off <<= 1) {
        const int x = (t >= off) ? sm[t - off] : 0;
        __syncthreads();
        sm[t] += x;
        __syncthreads();
    }
    if (i < NN) offs[i] = sm[t] - v;
    if (t == 255) bsum[blockIdx.x] = sm[255];
}

__global__ __launch_bounds__(512) void k_scan2(int* __restrict__ bsum) {
    __shared__ int sm[512];
    const int t = threadIdx.x;
    const int v = (t < NSB) ? bsum[t] : 0;
    sm[t] = v;
    __syncthreads();
    for (int off = 1; off < 512; off <<= 1) {
        const int x = (t >= off) ? sm[t - off] : 0;
        __syncthreads();
        sm[t] += x;
        __syncthreads();
    }
    if (t < NSB) bsum[t] = sm[t] - v;
}

__global__ __launch_bounds__(256) void k_scan3(int* __restrict__ offs,
                                               const int* __restrict__ bsum) {
    const int i = blockIdx.x * 256 + threadIdx.x;
    if (i < NN) offs[i] += bsum[blockIdx.x];
    if (i == 0) offs[NN] = NE;
}

// ---------------------------------------------------------------------------
// Fused: blocks [0,1250):    scatter meta[offs[d]+rank[e]] = {src, e5 bf16}
//                            (no atomics: rank precomputed; NT 16B stores)
//        blocks [1250,4375): MFMA projections layer 0 (overlapped)
__global__ __launch_bounds__(256) void k_scat_proj(const int* __restrict__ ei,
                                                   const float* __restrict__ eattr,
                                                   const float* __restrict__ sw,
                                                   const float* __restrict__ sb,
                                                   const int* __restrict__ rank,
                                                   const int* __restrict__ offs,
                                                   unsigned* __restrict__ meta,
                                                   const unsigned short* __restrict__ xb,
                                                   const unsigned short* __restrict__ Bp,
                                                   const float* __restrict__ bfv,
                                                   const float* __restrict__ bsv,
                                                   unsigned* __restrict__ Pd,
                                                   unsigned* __restrict__ Ps) {
    __shared__ __align__(16) short xl[32 * 64];
    if (blockIdx.x < 1250) {
        __shared__ float swl[25], sbl[5];
        if (threadIdx.x < 25) swl[threadIdx.x] = sw[threadIdx.x];
        if (threadIdx.x >= 32 && threadIdx.x < 37) sbl[threadIdx.x - 32] = sb[threadIdx.x - 32];
        __syncthreads();
        const int base = blockIdx.x * 1280 + threadIdx.x;
        int s[5], d[5], r[5];
        float ea[5][5];
#pragma unroll
        for (int j = 0; j < 5; j++) {
            const int e = base + j * 256;
            s[j] = ei[e];
            d[j] = ei[NE + e];
            r[j] = rank[e];
#pragma unroll
            for (int k = 0; k < 5; k++) ea[j][k] = eattr[(size_t)e * 5 + k];
        }
        int pos[5];
#pragma unroll
        for (int j = 0; j < 5; j++) pos[j] = offs[d[j]] + r[j];  // random load, no RMW
#pragma unroll
        for (int j = 0; j < 5; j++) {
            unsigned u5[5];
#pragma unroll
            for (int k = 0; k < 5; k++) {
                float a = sbl[k];
#pragma unroll
                for (int q = 0; q < 5; q++) a += ea[j][q] * swl[q * 5 + k];
                u5[k] = f2bf(fmaxf(a, 0.f));
            }
            u32x4 m;
            m[0] = (unsigned)s[j];
            m[1] = u5[0] | (u5[1] << 16);
            m[2] = u5[2] | (u5[3] << 16);
            m[3] = u5[4];
            __builtin_nontemporal_store(m, (u32x4*)&meta[(size_t)pos[j] * 4]);
        }
        return;
    }
    // ---- projm path (layer 0) ----
    const int rowbase = (blockIdx.x - 1250) * 32;
    {
        const u32x4* xsrc = (const u32x4*)(xb + (size_t)rowbase * 64);  // 4096 B
        u32x4* xdst = (u32x4*)xl;
        xdst[threadIdx.x] = __builtin_nontemporal_load(&xsrc[threadIdx.x]);
    }
    __syncthreads();
    const int ct = threadIdx.x >> 6;
    const int l = threadIdx.x & 63;
    const int lm = l & 15;
    const int g = l >> 4;
    short8v A[2][2];
#pragma unroll
    for (int rt = 0; rt < 2; rt++) {
        const short* xrow = &xl[(rt * 16 + lm) * 64];
        A[rt][0] = mk8(*(const short4v*)&xrow[g * 4], *(const short4v*)&xrow[16 + g * 4]);
        A[rt][1] = mk8(*(const short4v*)&xrow[32 + g * 4], *(const short4v*)&xrow[48 + g * 4]);
    }
    const short* bp = (const short*)Bp;
    f32x4 acc[4][2];
#pragma unroll
    for (int m = 0; m < 4; m++) {
        const short8v B0 = *(const short8v*)&bp[(((m * 4 + ct) * 2 + 0) * 64 + l) * 8];
        const short8v B1 = *(const short8v*)&bp[(((m * 4 + ct) * 2 + 1) * 64 + l) * 8];
#pragma unroll
        for (int rt = 0; rt < 2; rt++) {
            f32x4 a = {0.f, 0.f, 0.f, 0.f};
            a = __builtin_amdgcn_mfma_f32_16x16x32_bf16(A[rt][0], B0, a, 0, 0, 0);
            a = __builtin_amdgcn_mfma_f32_16x16x32_bf16(A[rt][1], B1, a, 0, 0, 0);
            acc[m][rt] = a;
        }
    }
    const int col = ct * 16 + lm;
    const float bfb = -LOG2E * bfv[col];
    const float bsb = LOG2E * bsv[col];
#pragma unroll
    for (int rt = 0; rt < 2; rt++) {
#pragma unroll
        for (int reg = 0; reg < 4; reg++) {
            const int rowg = rowbase + rt * 16 + g * 4 + reg;
            Pd[(size_t)rowg * 64 + col] =
                f2bf(acc[0][rt][reg] + bfb) | (f2bf(acc[1][rt][reg] + bsb) << 16);
            Ps[(size_t)rowg * 64 + col] =
                f2bf(acc[2][rt][reg]) | (f2bf(acc[3][rt][reg]) << 16);
        }
    }
}

// ---------------------------------------------------------------------------
// MFMA projections (standalone, layer 1), 32 rows per block.
__global__ __launch_bounds__(256) void k_projm(const unsigned short* __restrict__ xb,
                                               const unsigned short* __restrict__ Bp,
                                               const float* __restrict__ bfv,
                                               const float* __restrict__ bsv,
                                               unsigned* __restrict__ Pd,
                                               unsigned* __restrict__ Ps) {
    __shared__ __align__(16) short xl[32 * 64];
    const int rowbase = blockIdx.x * 32;
    {
        const u32x4* xsrc = (const u32x4*)(xb + (size_t)rowbase * 64);
        u32x4* xdst = (u32x4*)xl;
        xdst[threadIdx.x] = __builtin_nontemporal_load(&xsrc[threadIdx.x]);
    }
    __syncthreads();
    const int ct = threadIdx.x >> 6;
    const int l = threadIdx.x & 63;
    const int lm = l & 15;
    const int g = l >> 4;
    short8v A[2][2];
#pragma unroll
    for (int rt = 0; rt < 2; rt++) {
        const short* xrow = &xl[(rt * 16 + lm) * 64];
        A[rt][0] = mk8(*(const short4v*)&xrow[g * 4], *(const short4v*)&xrow[16 + g * 4]);
        A[rt][1] = mk8(*(const short4v*)&xrow[32 + g * 4], *(const short4v*)&xrow[48 + g * 4]);
    }
    const short* bp = (const short*)Bp;
    f32x4 acc[4][2];
#pragma unroll
    for (int m = 0; m < 4; m++) {
        const short8v B0 = *(const short8v*)&bp[(((m * 4 + ct) * 2 + 0) * 64 + l) * 8];
        const short8v B1 = *(const short8v*)&bp[(((m * 4 + ct) * 2 + 1) * 64 + l) * 8];
#pragma unroll
        for (int rt = 0; rt < 2; rt++) {
            f32x4 a = {0.f, 0.f, 0.f, 0.f};
            a = __builtin_amdgcn_mfma_f32_16x16x32_bf16(A[rt][0], B0, a, 0, 0, 0);
            a = __builtin_amdgcn_mfma_f32_16x16x32_bf16(A[rt][1], B1, a, 0, 0, 0);
            acc[m][rt] = a;
        }
    }
    const int col = ct * 16 + lm;
    const float bfb = -LOG2E * bfv[col];
    const float bsb = LOG2E * bsv[col];
#pragma unroll
    for (int rt = 0; rt < 2; rt++) {
#pragma unroll
        for (int reg = 0; reg < 4; reg++) {
            const int rowg = rowbase + rt * 16 + g * 4 + reg;
            Pd[(size_t)rowg * 64 + col] =
                f2bf(acc[0][rt][reg] + bfb) | (f2bf(acc[1][rt][reg] + bsb) << 16);
            Ps[(size_t)rowg * 64 + col] =
                f2bf(acc[2][rt][reg]) | (f2bf(acc[3][rt][reg]) << 16);
        }
    }
}

// ---------------------------------------------------------------------------
// Segment aggregation: one wave per dst node, edges pre-sorted by dst.
// 4-wide batched pipeline: meta prefetched 2 batches ahead (scalar loads),
// 4 independent Ps gathers in flight; peeled predicated last batch.
__global__ __launch_bounds__(256) void k_seg(const int* __restrict__ offs,
                                             const uint4* __restrict__ meta,
                                             const unsigned* __restrict__ Pd,
                                             const unsigned* __restrict__ Ps,
                                             const float* __restrict__ wfE,
                                             const float* __restrict__ wsE,
                                             const float* __restrict__ xin,
                                             float* __restrict__ out,
                                             unsigned short* __restrict__ xbout) {
    __shared__ float wfl[320], wsl[320];
    for (int i = threadIdx.x; i < 320; i += 256) {
        wfl[i] = -LOG2E * wfE[i];
        wsl[i] = LOG2E * wsE[i];
    }
    __syncthreads();
    const int n = blockIdx.x * 4 + (threadIdx.x >> 6);
    const int lane = threadIdx.x & 63;
    const int start = __builtin_amdgcn_readfirstlane(offs[n]);
    const int end = __builtin_amdgcn_readfirstlane(offs[n + 1]);
    const unsigned pd = __builtin_nontemporal_load(&Pd[(size_t)n * 64 + lane]);
    const float npdf = bflo(pd);
    const float pds = bfhi(pd);
    float wfv[5], wsv[5];
#pragma unroll
    for (int k = 0; k < 5; k++) {
        wfv[k] = wfl[k * 64 + lane];
        wsv[k] = wsl[k * 64 + lane];
    }
    const float xv = __builtin_nontemporal_load(&xin[(size_t)n * 64 + lane]);
    float acc = 0.f;
    const int cnt = end - start;
    if (cnt > 0) {
        const int last = end - 1;
        const int nbF = (cnt + 3) >> 2;
        uint4 M0[4], M1[4];
        unsigned PS0[4];
#pragma unroll
        for (int j = 0; j < 4; j++) M0[j] = meta[imin(start + j, last)];
#pragma unroll
        for (int j = 0; j < 4; j++) M1[j] = meta[imin(start + 4 + j, last)];
#pragma unroll
        for (int j = 0; j < 4; j++) PS0[j] = Ps[(size_t)M0[j].x * 64 + lane];
        for (int b = 0; b < nbF - 1; b++) {
            const int base2 = start + (b + 2) * 4;
            uint4 M2[4];
            unsigned PS1[4];
#pragma unroll
            for (int j = 0; j < 4; j++) M2[j] = meta[imin(base2 + j, last)];
#pragma unroll
            for (int j = 0; j < 4; j++) PS1[j] = Ps[(size_t)M1[j].x * 64 + lane];
#pragma unroll
            for (int j = 0; j < 4; j++) acc = edge_acc(M0[j], PS0[j], npdf, pds, wfv, wsv, acc);
#pragma unroll
            for (int j = 0; j < 4; j++) {
                M0[j] = M1[j];
                M1[j] = M2[j];
                PS0[j] = PS1[j];
            }
        }
        const int lb = start + (nbF - 1) * 4;
#pragma unroll
        for (int j = 0; j < 4; j++)
            if (lb + j < end) acc = edge_acc(M0[j], PS0[j], npdf, pds, wfv, wsv, acc);
    }
    const float res = fmaxf(fmaf(acc, LN2, xv), 0.f);
    if (xbout) {
        out[(size_t)n * 64 + lane] = res;  // X1: re-read next layer, keep cached
        xbout[(size_t)n * 64 + lane] = (unsigned short)f2bf(res);
    } else {
        __builtin_nontemporal_store(res, &out[(size_t)n * 64 + lane]);  // final output
    }
}

// ---------------------------------------------------------------------------
extern "C" void kernel_launch(void* const* d_in, const int* in_sizes, int n_in,
                              void* d_out, int out_size, void* d_ws, size_t ws_size,
                              hipStream_t stream) {
    const float* h = (const float*)d_in[0];
    const int* ei = (const int*)d_in[1];
    const float* eattr = (const float*)d_in[3];
    const float* lin0_w = (const float*)d_in[5];
    const float* lin0_b = (const float*)d_in[6];
    const float* short_w = (const float*)d_in[7];
    const float* short_b = (const float*)d_in[8];
    const float* conv_f_w = (const float*)d_in[9];
    const float* conv_f_b = (const float*)d_in[10];
    const float* conv_s_w = (const float*)d_in[11];
    const float* conv_s_b = (const float*)d_in[12];

    char* ws = (char*)d_ws;
    uint4* meta = (uint4*)ws;                             // [NE] 16B, 25.6 MB
    float* X0 = (float*)(ws + (size_t)NE * 16);           // [NN*64] f32
    float* X1 = X0 + (size_t)NN * 64;                     // [NN*64] f32
    unsigned* Pd = (unsigned*)(X1 + (size_t)NN * 64);     // [NN*64] u32
    unsigned* Ps = Pd + (size_t)NN * 64;                  // [NN*64] u32
    unsigned short* XB = (unsigned short*)(Ps + (size_t)NN * 64);  // [NN*64] bf16
    unsigned short* Bp = XB + (size_t)NN * 64;            // [2][16384]+[4096] packed weights
    int* cnt = (int*)(Bp + 36864);                        // [NN]
    int* offs = cnt + NN;                                 // [NN+1]
    int* bsum = offs + NN + 1;                            // [NSB]
    int* rank = (int*)X1;  // [NE] — aliased: rank dies before seg0 writes X1

    hipMemsetAsync(cnt, 0, (size_t)NN * 4, stream);
    k_wpack<<<18, 256, 0, stream>>>(conv_f_w, conv_s_w, lin0_w, Bp);
    k_lin0m_hist<<<1250 + 3125, 256, 0, stream>>>(h, Bp + 32768, lin0_b, X0, XB, ei, cnt, rank);
    k_scan1<<<NSB, 256, 0, stream>>>(cnt, offs, bsum);
    k_scan2<<<1, 512, 0, stream>>>(bsum);
    k_scan3<<<NSB, 256, 0, stream>>>(offs, bsum);
    // layer 0: scatter fused with projm (independent work, overlapped)
    k_scat_proj<<<1250 + 3125, 256, 0, stream>>>(ei, eattr, short_w, short_b, rank, offs,
                                                 (unsigned*)meta, XB, Bp, conv_f_b, conv_s_b,
                                                 Pd, Ps);
    k_seg<<<NN / 4, 256, 0, stream>>>(offs, meta, Pd, Ps,
                                      conv_f_w + 128 * 64, conv_s_w + 128 * 64,
                                      X0, X1, XB);
    // layer 1
    k_projm<<<NN / 32, 256, 0, stream>>>(XB, Bp + 16384, conv_f_b + 64, conv_s_b + 64, Pd, Ps);
    k_seg<<<NN / 4, 256, 0, stream>>>(offs, meta, Pd, Ps,
                                      conv_f_w + 133 * 64 + 128 * 64,
                                      conv_s_w + 133 * 64 + 128 * 64,
                                      X1, (float*)d_out, (unsigned short*)nullptr);
}

// Round 10
// 352.552 us; speedup vs baseline: 4.0218x; 1.0201x over previous
//
#include <hip/hip_runtime.h>

#define NN 100000
#define NE 1600000
#define NSB 391  // ceil(NN/256) scan blocks

#define LOG2E 1.4426950408889634f
#define LN2 0.6931471805599453f

typedef short short4v __attribute__((ext_vector_type(4)));
typedef short short8v __attribute__((ext_vector_type(8)));
typedef float f32x2 __attribute__((ext_vector_type(2)));
typedef float f32x4 __attribute__((ext_vector_type(4)));
typedef unsigned u32x4 __attribute__((ext_vector_type(4)));

static __device__ __forceinline__ unsigned f2bf(float x) {
    unsigned b = __float_as_uint(x);
    return (b + 0x7FFFu + ((b >> 16) & 1u)) >> 16;  // RNE bf16 bits
}
static __device__ __forceinline__ float bflo(unsigned u) { return __uint_as_float(u << 16); }
static __device__ __forceinline__ float bfhi(unsigned u) { return __uint_as_float(u & 0xFFFF0000u); }
static __device__ __forceinline__ int imin(int a, int b) { return a < b ? a : b; }
static __device__ __forceinline__ short8v mk8(short4v a, short4v b) {
    short8v r;
    r[0] = a[0]; r[1] = a[1]; r[2] = a[2]; r[3] = a[3];
    r[4] = b[0]; r[5] = b[1]; r[6] = b[2]; r[7] = b[3];
    return r;
}

// One edge's gated-message contribution; dual (zf,zs) chain as float2 so the
// compiler can emit v_pk_fma_f32 (VOP3P). True msg sum = LN2 * returned acc.
static __device__ __forceinline__ float edge_acc(uint4 m, unsigned ps, f32x2 pd2,
                                                 const f32x2* __restrict__ w2, float acc) {
    f32x2 z;
    z.x = bflo(ps);
    z.y = bfhi(ps);
    z += pd2;
    const float e50 = bflo(m.y), e51 = bfhi(m.y);
    const float e52 = bflo(m.z), e53 = bfhi(m.z);
    const float e54 = bflo(m.w);
    z += e50 * w2[0];
    z += e51 * w2[1];
    z += e52 * w2[2];
    z += e53 * w2[3];
    z += e54 * w2[4];
    const float sig = __builtin_amdgcn_rcpf(1.f + __builtin_amdgcn_exp2f(z.x));
    const float gg = fmaxf(z.y, 0.f) +
                     __builtin_amdgcn_logf(1.f + __builtin_amdgcn_exp2f(-fabsf(z.y)));
    return fmaf(sig, gg, acc);
}

// ---------------------------------------------------------------------------
// Pack into MFMA B-fragment layout:
//   qq in [0,4096): 2 conv layers x 4 mats (0=dstF 1=dstS 2=srcF 3=srcS),
//                   LOG2E-scaled/sign-folded
//   qq in [4096,4608): lin0_w, unscaled
__global__ __launch_bounds__(256) void k_wpack(const float* __restrict__ cfw,
                                               const float* __restrict__ csw,
                                               const float* __restrict__ l0w,
                                               unsigned short* __restrict__ Bp) {
    const int qq = blockIdx.x * 256 + threadIdx.x;  // 4608 total
    const float* src;
    float scale;
    int roff, ct, kh, l;
    if (qq < 4096) {
        const int layer = qq >> 11;
        const int q = qq & 2047;
        const int m = q >> 9;
        const int rem = q & 511;
        ct = rem >> 7;
        kh = (rem >> 6) & 1;
        l = rem & 63;
        scale = (m & 1) ? LOG2E : -LOG2E;
        src = ((m & 1) ? csw : cfw) + (size_t)layer * 133 * 64;
        roff = (m >> 1) ? 64 : 0;
    } else {
        const int p = qq - 4096;
        ct = p >> 7;
        kh = (p >> 6) & 1;
        l = p & 63;
        scale = 1.f;
        src = l0w;
        roff = 0;
    }
    const int n = ct * 16 + (l & 15);
#pragma unroll
    for (int j = 0; j < 8; j++) {
        const int k = kh * 32 + ((j < 4) ? (4 * (l >> 4) + j) : (16 + 4 * (l >> 4) + j - 4));
        Bp[(size_t)qq * 8 + j] = (unsigned short)f2bf(scale * src[(size_t)(roff + k) * 64 + n]);
    }
}

// ---------------------------------------------------------------------------
// Fused: blocks [0,1250):    dst histogram + per-edge rank (5 edges/thread;
//                            latency-bound, overlaps with lin0 MFMA blocks)
//        blocks [1250,4375): X0 = relu(h @ lin0_w + b) via MFMA, 32 rows/block
__global__ __launch_bounds__(256) void k_lin0m_hist(const float* __restrict__ h,
                                                    const unsigned short* __restrict__ Bp0,
                                                    const float* __restrict__ b,
                                                    float* __restrict__ x0,
                                                    unsigned short* __restrict__ xb,
                                                    const int* __restrict__ ei,
                                                    int* __restrict__ cnt,
                                                    int* __restrict__ rank) {
    __shared__ __align__(16) short xl[32 * 64];
    if (blockIdx.x < 1250) {
        const int base = blockIdx.x * 1280 + threadIdx.x;
        int r[5];
#pragma unroll
        for (int j = 0; j < 5; j++) r[j] = atomicAdd(&cnt[ei[NE + base + j * 256]], 1);
#pragma unroll
        for (int j = 0; j < 5; j++) rank[base + j * 256] = r[j];
        return;
    }
    const int rowbase = (blockIdx.x - 1250) * 32;
    // stage 32x64 h-tile as bf16 (coalesced float4 loads)
    {
        const float4* hs = (const float4*)(h + (size_t)rowbase * 64);
#pragma unroll
        for (int it = 0; it < 2; it++) {
            const float4 v = hs[threadIdx.x + it * 256];
            short4v sv;
            sv[0] = (short)f2bf(v.x);
            sv[1] = (short)f2bf(v.y);
            sv[2] = (short)f2bf(v.z);
            sv[3] = (short)f2bf(v.w);
            *(short4v*)&xl[(threadIdx.x + it * 256) * 4] = sv;
        }
    }
    __syncthreads();
    const int ct = threadIdx.x >> 6;
    const int l = threadIdx.x & 63;
    const int lm = l & 15;
    const int g = l >> 4;
    short8v A[2][2];
#pragma unroll
    for (int rt = 0; rt < 2; rt++) {
        const short* xrow = &xl[(rt * 16 + lm) * 64];
        A[rt][0] = mk8(*(const short4v*)&xrow[g * 4], *(const short4v*)&xrow[16 + g * 4]);
        A[rt][1] = mk8(*(const short4v*)&xrow[32 + g * 4], *(const short4v*)&xrow[48 + g * 4]);
    }
    const short* bp = (const short*)Bp0;
    const short8v B0 = *(const short8v*)&bp[((ct * 2 + 0) * 64 + l) * 8];
    const short8v B1 = *(const short8v*)&bp[((ct * 2 + 1) * 64 + l) * 8];
    const int col = ct * 16 + lm;
    const float bc = b[col];
#pragma unroll
    for (int rt = 0; rt < 2; rt++) {
        f32x4 a = {0.f, 0.f, 0.f, 0.f};
        a = __builtin_amdgcn_mfma_f32_16x16x32_bf16(A[rt][0], B0, a, 0, 0, 0);
        a = __builtin_amdgcn_mfma_f32_16x16x32_bf16(A[rt][1], B1, a, 0, 0, 0);
#pragma unroll
        for (int reg = 0; reg < 4; reg++) {
            const int rowg = rowbase + rt * 16 + g * 4 + reg;
            const float r = fmaxf(a[reg] + bc, 0.f);
            x0[(size_t)rowg * 64 + col] = r;
            xb[(size_t)rowg * 64 + col] = (unsigned short)f2bf(r);
        }
    }
}

// ---------------------------------------------------------------------------
__global__ __launch_bounds__(256) void k_scan1(const int* __restrict__ cnt,
                                               int* __restrict__ offs, int* __restrict__ bsum) {
    __shared__ int sm[256];
    const int t = threadIdx.x;
    const int i = blockIdx.x * 256 + t;
    const int v = (i < NN) ? cnt[i] : 0;
    sm[t] = v;
    __syncthreads();
    for (int off = 1; off < 256; off <<= 1) {
        const int x = (t >= off) ? sm[t - off] : 0;
        __syncthreads();
        sm[t] += x;
        __syncthreads();
    }
    if (i < NN) offs[i] = sm[t] - v;
    if (t == 255) bsum[blockIdx.x] = sm[255];
}

__global__ __launch_bounds__(512) void k_scan2(int* __restrict__ bsum) {
    __shared__ int sm[512];
    const int t = threadIdx.x;
    const int v = (t < NSB) ? bsum[t] : 0;
    sm[t] = v;
    __syncthreads();
    for (int off = 1; off < 512; off <<= 1) {
        const int x = (t >= off) ? sm[t - off] : 0;
        __syncthreads();
        sm[t] += x;
        __syncthreads();
    }
    if (t < NSB) bsum[t] = sm[t] - v;
}

__global__ __launch_bounds__(256) void k_scan3(int* __restrict__ offs,
                                               const int* __restrict__ bsum) {
    const int i = blockIdx.x * 256 + threadIdx.x;
    if (i < NN) offs[i] += bsum[blockIdx.x];
    if (i == 0) offs[NN] = NE;
}

// ---------------------------------------------------------------------------
// Fused: blocks [0,1250):    scatter meta[offs[d]+rank[e]] = {src, e5 bf16}
//                            (no atomics: rank precomputed; NT 16B stores)
//        blocks [1250,4375): MFMA projections layer 0 (overlapped)
__global__ __launch_bounds__(256) void k_scat_proj(const int* __restrict__ ei,
                                                   const float* __restrict__ eattr,
                                                   const float* __restrict__ sw,
                                                   const float* __restrict__ sb,
                                                   const int* __restrict__ rank,
                                                   const int* __restrict__ offs,
                                                   unsigned* __restrict__ meta,
                                                   const unsigned short* __restrict__ xb,
                                                   const unsigned short* __restrict__ Bp,
                                                   const float* __restrict__ bfv,
                                                   const float* __restrict__ bsv,
                                                   unsigned* __restrict__ Pd,
                                                   unsigned* __restrict__ Ps) {
    __shared__ __align__(16) short xl[32 * 64];
    if (blockIdx.x < 1250) {
        __shared__ float swl[25], sbl[5];
        if (threadIdx.x < 25) swl[threadIdx.x] = sw[threadIdx.x];
        if (threadIdx.x >= 32 && threadIdx.x < 37) sbl[threadIdx.x - 32] = sb[threadIdx.x - 32];
        __syncthreads();
        const int base = blockIdx.x * 1280 + threadIdx.x;
        int s[5], d[5], r[5];
        float ea[5][5];
#pragma unroll
        for (int j = 0; j < 5; j++) {
            const int e = base + j * 256;
            s[j] = ei[e];
            d[j] = ei[NE + e];
            r[j] = rank[e];
#pragma unroll
            for (int k = 0; k < 5; k++) ea[j][k] = eattr[(size_t)e * 5 + k];
        }
        int pos[5];
#pragma unroll
        for (int j = 0; j < 5; j++) pos[j] = offs[d[j]] + r[j];  // random load, no RMW
#pragma unroll
        for (int j = 0; j < 5; j++) {
            unsigned u5[5];
#pragma unroll
            for (int k = 0; k < 5; k++) {
                float a = sbl[k];
#pragma unroll
                for (int q = 0; q < 5; q++) a += ea[j][q] * swl[q * 5 + k];
                u5[k] = f2bf(fmaxf(a, 0.f));
            }
            u32x4 m;
            m[0] = (unsigned)s[j];
            m[1] = u5[0] | (u5[1] << 16);
            m[2] = u5[2] | (u5[3] << 16);
            m[3] = u5[4];
            __builtin_nontemporal_store(m, (u32x4*)&meta[(size_t)pos[j] * 4]);
        }
        return;
    }
    // ---- projm path (layer 0) ----
    const int rowbase = (blockIdx.x - 1250) * 32;
    {
        const u32x4* xsrc = (const u32x4*)(xb + (size_t)rowbase * 64);  // 4096 B
        u32x4* xdst = (u32x4*)xl;
        xdst[threadIdx.x] = __builtin_nontemporal_load(&xsrc[threadIdx.x]);
    }
    __syncthreads();
    const int ct = threadIdx.x >> 6;
    const int l = threadIdx.x & 63;
    const int lm = l & 15;
    const int g = l >> 4;
    short8v A[2][2];
#pragma unroll
    for (int rt = 0; rt < 2; rt++) {
        const short* xrow = &xl[(rt * 16 + lm) * 64];
        A[rt][0] = mk8(*(const short4v*)&xrow[g * 4], *(const short4v*)&xrow[16 + g * 4]);
        A[rt][1] = mk8(*(const short4v*)&xrow[32 + g * 4], *(const short4v*)&xrow[48 + g * 4]);
    }
    const short* bp = (const short*)Bp;
    f32x4 acc[4][2];
#pragma unroll
    for (int m = 0; m < 4; m++) {
        const short8v B0 = *(const short8v*)&bp[(((m * 4 + ct) * 2 + 0) * 64 + l) * 8];
        const short8v B1 = *(const short8v*)&bp[(((m * 4 + ct) * 2 + 1) * 64 + l) * 8];
#pragma unroll
        for (int rt = 0; rt < 2; rt++) {
            f32x4 a = {0.f, 0.f, 0.f, 0.f};
            a = __builtin_amdgcn_mfma_f32_16x16x32_bf16(A[rt][0], B0, a, 0, 0, 0);
            a = __builtin_amdgcn_mfma_f32_16x16x32_bf16(A[rt][1], B1, a, 0, 0, 0);
            acc[m][rt] = a;
        }
    }
    const int col = ct * 16 + lm;
    const float bfb = -LOG2E * bfv[col];
    const float bsb = LOG2E * bsv[col];
#pragma unroll
    for (int rt = 0; rt < 2; rt++) {
#pragma unroll
        for (int reg = 0; reg < 4; reg++) {
            const int rowg = rowbase + rt * 16 + g * 4 + reg;
            Pd[(size_t)rowg * 64 + col] =
                f2bf(acc[0][rt][reg] + bfb) | (f2bf(acc[1][rt][reg] + bsb) << 16);
            Ps[(size_t)rowg * 64 + col] =
                f2bf(acc[2][rt][reg]) | (f2bf(acc[3][rt][reg]) << 16);
        }
    }
}

// ---------------------------------------------------------------------------
// MFMA projections (standalone, layer 1), 32 rows per block.
__global__ __launch_bounds__(256) void k_projm(const unsigned short* __restrict__ xb,
                                               const unsigned short* __restrict__ Bp,
                                               const float* __restrict__ bfv,
                                               const float* __restrict__ bsv,
                                               unsigned* __restrict__ Pd,
                                               unsigned* __restrict__ Ps) {
    __shared__ __align__(16) short xl[32 * 64];
    const int rowbase = blockIdx.x * 32;
    {
        const u32x4* xsrc = (const u32x4*)(xb + (size_t)rowbase * 64);
        u32x4* xdst = (u32x4*)xl;
        xdst[threadIdx.x] = __builtin_nontemporal_load(&xsrc[threadIdx.x]);
    }
    __syncthreads();
    const int ct = threadIdx.x >> 6;
    const int l = threadIdx.x & 63;
    const int lm = l & 15;
    const int g = l >> 4;
    short8v A[2][2];
#pragma unroll
    for (int rt = 0; rt < 2; rt++) {
        const short* xrow = &xl[(rt * 16 + lm) * 64];
        A[rt][0] = mk8(*(const short4v*)&xrow[g * 4], *(const short4v*)&xrow[16 + g * 4]);
        A[rt][1] = mk8(*(const short4v*)&xrow[32 + g * 4], *(const short4v*)&xrow[48 + g * 4]);
    }
    const short* bp = (const short*)Bp;
    f32x4 acc[4][2];
#pragma unroll
    for (int m = 0; m < 4; m++) {
        const short8v B0 = *(const short8v*)&bp[(((m * 4 + ct) * 2 + 0) * 64 + l) * 8];
        const short8v B1 = *(const short8v*)&bp[(((m * 4 + ct) * 2 + 1) * 64 + l) * 8];
#pragma unroll
        for (int rt = 0; rt < 2; rt++) {
            f32x4 a = {0.f, 0.f, 0.f, 0.f};
            a = __builtin_amdgcn_mfma_f32_16x16x32_bf16(A[rt][0], B0, a, 0, 0, 0);
            a = __builtin_amdgcn_mfma_f32_16x16x32_bf16(A[rt][1], B1, a, 0, 0, 0);
            acc[m][rt] = a;
        }
    }
    const int col = ct * 16 + lm;
    const float bfb = -LOG2E * bfv[col];
    const float bsb = LOG2E * bsv[col];
#pragma unroll
    for (int rt = 0; rt < 2; rt++) {
#pragma unroll
        for (int reg = 0; reg < 4; reg++) {
            const int rowg = rowbase + rt * 16 + g * 4 + reg;
            Pd[(size_t)rowg * 64 + col] =
                f2bf(acc[0][rt][reg] + bfb) | (f2bf(acc[1][rt][reg] + bsb) << 16);
            Ps[(size_t)rowg * 64 + col] =
                f2bf(acc[2][rt][reg]) | (f2bf(acc[3][rt][reg]) << 16);
        }
    }
}

// ---------------------------------------------------------------------------
// Segment aggregation: one wave per dst node, edges pre-sorted by dst.
// 4-wide batched pipeline (meta 2 batches ahead via scalarized s_load path,
// 4 Ps gathers in flight), float2 packed (zf,zs) math, peeled last batch.
__global__ __launch_bounds__(256) void k_seg(const int* __restrict__ offs,
                                             const uint4* __restrict__ meta,
                                             const unsigned* __restrict__ Pd,
                                             const unsigned* __restrict__ Ps,
                                             const float* __restrict__ wfE,
                                             const float* __restrict__ wsE,
                                             const float* __restrict__ xin,
                                             float* __restrict__ out,
                                             unsigned short* __restrict__ xbout) {
    __shared__ f32x2 wl2[320];
    for (int i = threadIdx.x; i < 320; i += 256) {
        f32x2 p;
        p.x = -LOG2E * wfE[i];
        p.y = LOG2E * wsE[i];
        wl2[i] = p;
    }
    __syncthreads();
    const int n = blockIdx.x * 4 + (threadIdx.x >> 6);
    const int lane = threadIdx.x & 63;
    const int start = __builtin_amdgcn_readfirstlane(offs[n]);
    const int end = __builtin_amdgcn_readfirstlane(offs[n + 1]);
    const unsigned pd = __builtin_nontemporal_load(&Pd[(size_t)n * 64 + lane]);
    f32x2 pd2;
    pd2.x = bflo(pd);
    pd2.y = bfhi(pd);
    f32x2 w2[5];
#pragma unroll
    for (int k = 0; k < 5; k++) w2[k] = wl2[k * 64 + lane];
    const float xv = __builtin_nontemporal_load(&xin[(size_t)n * 64 + lane]);
    float acc = 0.f;
    const int cnt = end - start;
    if (cnt > 0) {
        const int last = end - 1;
        const int nbF = (cnt + 3) >> 2;
        uint4 M0[4], M1[4];
        unsigned PS0[4];
#pragma unroll
        for (int j = 0; j < 4; j++) M0[j] = meta[imin(start + j, last)];
#pragma unroll
        for (int j = 0; j < 4; j++) M1[j] = meta[imin(start + 4 + j, last)];
#pragma unroll
        for (int j = 0; j < 4; j++) PS0[j] = Ps[(size_t)M0[j].x * 64 + lane];
        for (int b = 0; b < nbF - 1; b++) {
            const int base2 = __builtin_amdgcn_readfirstlane(start + (b + 2) * 4);
            uint4 M2[4];
            unsigned PS1[4];
#pragma unroll
            for (int j = 0; j < 4; j++) M2[j] = meta[imin(base2 + j, last)];
#pragma unroll
            for (int j = 0; j < 4; j++) PS1[j] = Ps[(size_t)M1[j].x * 64 + lane];
#pragma unroll
            for (int j = 0; j < 4; j++) acc = edge_acc(M0[j], PS0[j], pd2, w2, acc);
#pragma unroll
            for (int j = 0; j < 4; j++) {
                M0[j] = M1[j];
                M1[j] = M2[j];
                PS0[j] = PS1[j];
            }
        }
        const int lb = start + (nbF - 1) * 4;
#pragma unroll
        for (int j = 0; j < 4; j++)
            if (lb + j < end) acc = edge_acc(M0[j], PS0[j], pd2, w2, acc);
    }
    const float res = fmaxf(fmaf(acc, LN2, xv), 0.f);
    if (xbout) {
        out[(size_t)n * 64 + lane] = res;  // X1: re-read next layer, keep cached
        xbout[(size_t)n * 64 + lane] = (unsigned short)f2bf(res);
    } else {
        __builtin_nontemporal_store(res, &out[(size_t)n * 64 + lane]);  // final output
    }
}

// ---------------------------------------------------------------------------
extern "C" void kernel_launch(void* const* d_in, const int* in_sizes, int n_in,
                              void* d_out, int out_size, void* d_ws, size_t ws_size,
                              hipStream_t stream) {
    const float* h = (const float*)d_in[0];
    const int* ei = (const int*)d_in[1];
    const float* eattr = (const float*)d_in[3];
    const float* lin0_w = (const float*)d_in[5];
    const float* lin0_b = (const float*)d_in[6];
    const float* short_w = (const float*)d_in[7];
    const float* short_b = (const float*)d_in[8];
    const float* conv_f_w = (const float*)d_in[9];
    const float* conv_f_b = (const float*)d_in[10];
    const float* conv_s_w = (const float*)d_in[11];
    const float* conv_s_b = (const float*)d_in[12];

    char* ws = (char*)d_ws;
    uint4* meta = (uint4*)ws;                             // [NE] 16B, 25.6 MB
    float* X0 = (float*)(ws + (size_t)NE * 16);           // [NN*64] f32
    float* X1 = X0 + (size_t)NN * 64;                     // [NN*64] f32
    unsigned* Pd = (unsigned*)(X1 + (size_t)NN * 64);     // [NN*64] u32
    unsigned* Ps = Pd + (size_t)NN * 64;                  // [NN*64] u32
    unsigned short* XB = (unsigned short*)(Ps + (size_t)NN * 64);  // [NN*64] bf16
    unsigned short* Bp = XB + (size_t)NN * 64;            // [2][16384]+[4096] packed weights
    int* cnt = (int*)(Bp + 36864);                        // [NN]
    int* offs = cnt + NN;                                 // [NN+1]
    int* bsum = offs + NN + 1;                            // [NSB]
    int* rank = (int*)X1;  // [NE] — aliased: rank dies before seg0 writes X1

    hipMemsetAsync(cnt, 0, (size_t)NN * 4, stream);
    k_wpack<<<18, 256, 0, stream>>>(conv_f_w, conv_s_w, lin0_w, Bp);
    k_lin0m_hist<<<1250 + 3125, 256, 0, stream>>>(h, Bp + 32768, lin0_b, X0, XB, ei, cnt, rank);
    k_scan1<<<NSB, 256, 0, stream>>>(cnt, offs, bsum);
    k_scan2<<<1, 512, 0, stream>>>(bsum);
    k_scan3<<<NSB, 256, 0, stream>>>(offs, bsum);
    // layer 0: scatter fused with projm (independent work, overlapped)
    k_scat_proj<<<1250 + 3125, 256, 0, stream>>>(ei, eattr, short_w, short_b, rank, offs,
                                                 (unsigned*)meta, XB, Bp, conv_f_b, conv_s_b,
                                                 Pd, Ps);
    k_seg<<<NN / 4, 256, 0, stream>>>(offs, meta, Pd, Ps,
                                      conv_f_w + 128 * 64, conv_s_w + 128 * 64,
                                      X0, X1, XB);
    // layer 1
    k_projm<<<NN / 32, 256, 0, stream>>>(XB, Bp + 16384, conv_f_b + 64, conv_s_b + 64, Pd, Ps);
    k_seg<<<NN / 4, 256, 0, stream>>>(offs, meta, Pd, Ps,
                                      conv_f_w + 133 * 64 + 128 * 64,
                                      conv_s_w + 133 * 64 + 128 * 64,
                                      X1, (float*)d_out, (unsigned short*)nullptr);
}